// Round 14
// baseline (540.271 us; speedup 1.0000x reference)
//
#include <hip/hip_runtime.h>
#include <hip/hip_bf16.h>

typedef unsigned short u16;
typedef unsigned int   u32;
typedef __attribute__((ext_vector_type(8))) short bf16x8;
typedef __attribute__((ext_vector_type(4))) float f32x4;

#define MFMA16(a,b,c) __builtin_amdgcn_mfma_f32_16x16x32_bf16((a),(b),(c),0,0,0)

__device__ __forceinline__ float b2f(u32 h){ return __uint_as_float(h<<16); }
__device__ __forceinline__ u16 f2b(float f){
  u32 u = __float_as_uint(f);
  return (u16)((u + 0x7FFFu + ((u>>16)&1u))>>16);
}
// HW packed convert: v_cvt_pk_bf16_f32 (RNE)
__device__ __forceinline__ u32 pk2f(float a,float b){
  __hip_bfloat162 h = __float22bfloat162_rn(float2{a,b});
  return *reinterpret_cast<u32*>(&h);
}
__device__ __forceinline__ u32 umin32(u32 a,u32 b){ return a<b?a:b; }
__device__ __forceinline__ u32 umax32(u32 a,u32 b){ return a>b?a:b; }

// 16-lane row-sum on the VALU pipe via DPP row_ror
template<int CTRL>
__device__ __forceinline__ float dpp_add(float x){
  int t = __builtin_amdgcn_update_dpp(0, __float_as_int(x), CTRL, 0xF, 0xF, true);
  return x + __int_as_float(t);
}
__device__ __forceinline__ float rowsum16(float x){
  x = dpp_add<0x121>(x);
  x = dpp_add<0x122>(x);
  x = dpp_add<0x124>(x);
  x = dpp_add<0x128>(x);
  return x;
}

__device__ __forceinline__ void async_copy16(const void* g, void* l){
  __builtin_amdgcn_global_load_lds((const __attribute__((address_space(1))) u32*)g,
                                   (__attribute__((address_space(3))) u32*)l, 16, 0, 0);
}

// ---------------- workspace layout (bytes) ----------------
#define OFF_IDX    0ull
#define OFF_FEATB  1048576ull
#define OFF_WPRE   3145728ull
#define OFF_WQKV   3178496ull
#define OFF_WA1    3571712ull
#define OFF_WA2    3702784ull
#define OFF_WP2    3833856ull
#define OFF_WPROJ  3964928ull
#define OFF_WPOST  4096000ull
#define OFF_MCOMB  4128768ull
#define OFF_INP    4259840ull
#define OFF_QKV    12648448ull     // hosts wp2T
#define OFF_LNQKV  37814272ull
#define OFF_QA     62980096ull
#define OFF_KA     71368704ull
#define OFF_RES    79757312ull
#define OFF_D1     88145920ull     // hosts wp1pk
#define OFF_R1     96534528ull
#define WS_NEED    104923136ull
#define OFF_WP1PK  OFF_D1
#define OFF_WP2T   OFF_QKV

// ---------------- f32 -> bf16 conversions + wp1 pack + wp2 transpose (fused) ----------------
__global__ void convert_k(const float* __restrict__ feat, const float* __restrict__ wpre,
    const float* __restrict__ wq, const float* __restrict__ wk, const float* __restrict__ wv,
    const float* __restrict__ wa1, const float* __restrict__ wa2, const float* __restrict__ wp2,
    const float* __restrict__ wproj, const float* __restrict__ wpost,
    const float* __restrict__ wp1,
    u16* __restrict__ dfeat, u16* __restrict__ dwpre, u16* __restrict__ dwqkv,
    u16* __restrict__ dwa1, u16* __restrict__ dwa2, u16* __restrict__ dwp2,
    u16* __restrict__ dwproj, u16* __restrict__ dwpost,
    u16* __restrict__ dwp1pk, u16* __restrict__ dwp2T){
  __shared__ u16 t[32][33];
  const int bid = blockIdx.x, tid = threadIdx.x;
  if (bid < 6016){
    int id = bid*256 + tid;
    const float* s; u16* d; int off;
    if      (id < 1048576){ s=feat;  d=dfeat;        off=id; }
    else if (id < 1064960){ s=wpre;  d=dwpre;        off=id-1048576; }
    else if (id < 1130496){ s=wq;    d=dwqkv;        off=id-1064960; }
    else if (id < 1196032){ s=wk;    d=dwqkv+65536;  off=id-1130496; }
    else if (id < 1261568){ s=wv;    d=dwqkv+131072; off=id-1196032; }
    else if (id < 1327104){ s=wa1;   d=dwa1;         off=id-1261568; }
    else if (id < 1392640){ s=wa2;   d=dwa2;         off=id-1327104; }
    else if (id < 1458176){ s=wp2;   d=dwp2;         off=id-1392640; }
    else if (id < 1523712){ s=wproj; d=dwproj;       off=id-1458176; }
    else if (id < 1540096){ s=wpost; d=dwpost;       off=id-1523712; }
    else return;
    d[off] = f2b(s[off]);
  } else if (bid == 6016){
    const int h = tid;
    const float w0 = wp1[h*3], w1 = wp1[h*3+1], w2 = wp1[h*3+2];
    uint4 a; a.x = pk2f(w0,w1); a.y = pk2f(w2,0.f); a.z = 0u; a.w = 0u;
    uint4 z; z.x = z.y = z.z = z.w = 0u;
    *(uint4*)&dwp1pk[h*32]    = a;
    *(uint4*)&dwp1pk[h*32+8]  = z;
    *(uint4*)&dwp1pk[h*32+16] = z;
    *(uint4*)&dwp1pk[h*32+24] = z;
  } else {
    const int tb = bid - 6017;
    const int bx = tb & 7, by = tb >> 3;
    const int tx = tid & 31, ty = tid >> 5;
    #pragma unroll
    for (int r = 0; r < 4; ++r) t[ty+8*r][tx] = f2b(wp2[(by*32+ty+8*r)*256 + bx*32+tx]);
    __syncthreads();
    #pragma unroll
    for (int r = 0; r < 4; ++r) dwp2T[(bx*32+ty+8*r)*256 + by*32+tx] = t[tx][ty+8*r];
  }
}

// ---------------- kNN: exact top-16 by (d2, idx) ----------------
__device__ __forceinline__ void ins16(u32 (&a)[16], u32 key){
  #pragma unroll
  for (int j = 15; j >= 1; --j) a[j] = umin32(umax32(a[j-1],key), a[j]);
  a[0] = umin32(a[0], key);
}

__device__ __forceinline__ float dist2(float ax,float ay,float az,float bx,float by,float bz){
  const float dx = ax-bx, dy = ay-by, dz = az-bz;
  return __fmaf_rn(dx,dx, __fmaf_rn(dy,dy, dz*dz));
}

__global__ __launch_bounds__(256,3) void knn_kernel(const float* __restrict__ xyz,
                                                    int* __restrict__ idxout){
  __shared__ __attribute__((aligned(16))) float sbuf[3*4104];
  __shared__ int lcnt[16];
  __shared__ int tcnt[16];
  __shared__ u32 tbuf[16];
  __shared__ int tiebuf[16*16];
  float* sx = sbuf; float* sy = sbuf + 4104; float* sz = sbuf + 8208;
  const int tid = threadIdx.x;
  const int b  = blockIdx.x >> 8;
  const int n0 = (blockIdx.x & 255) << 4;
  const float* base = xyz + (size_t)b*12288;
  #pragma unroll
  for (int i = 0; i < 12; ++i){
    const float4 v = *(const float4*)(base + tid*48 + i*4);
    const float vv[4] = {v.x, v.y, v.z, v.w};
    #pragma unroll
    for (int j = 0; j < 4; ++j){
      const int e = i*4 + j;
      const int c = e % 3;
      const int m = tid*16 + e/3;
      float* arr = (c==0)?sx:((c==1)?sy:sz);
      arr[m + (m>>9)] = vv[j];
    }
  }
  if (tid < 16){ lcnt[tid] = 0; tcnt[tid] = 0; }
  __syncthreads();
  const int qi = tid >> 4, p = tid & 15;
  const int n = n0 + qi;
  const int sn = n + (n>>9);
  const float qx = sx[sn], qy = sy[sn], qz = sz[sn];
  u32 a[16];
  #pragma unroll
  for (int j = 0; j < 16; ++j) a[j] = 0xFFFFFFFFu;
  const int sb = p*256 + (p>>1);
  #pragma unroll 2
  for (int i = 0; i < 256; ++i){
    const float d2 = dist2(sx[sb+i],sy[sb+i],sz[sb+i],qx,qy,qz);
    ins16(a, __float_as_uint(d2));
  }
  #pragma unroll
  for (int s = 8; s >= 1; s >>= 1){
    u32 o[16];
    #pragma unroll
    for (int j = 0; j < 16; ++j) o[j] = __shfl_down(a[j], (unsigned)s, 64);
    if (p < s){
      #pragma unroll
      for (int j = 0; j < 16; ++j) ins16(a, o[j]);
    }
  }
  if (p == 0) tbuf[qi] = a[15];
  __syncthreads();
  const u32 T = tbuf[qi];
  int* orow = idxout + ((size_t)(b<<12)+n)*16;
  const int gbase = p*256;
  for (int i = 0; i < 256; ++i){
    const float d2 = dist2(sx[sb+i],sy[sb+i],sz[sb+i],qx,qy,qz);
    const u32 kb = __float_as_uint(d2);
    if (kb < T){
      const int pos = atomicAdd(&lcnt[qi],1);
      if (pos < 16) orow[pos] = gbase + i;
    } else if (kb == T){
      const int t = atomicAdd(&tcnt[qi],1);
      if (t < 16) tiebuf[qi*16+t] = gbase + i;
    }
  }
  __syncthreads();
  if (p == 0){
    int L = lcnt[qi]; if (L > 16) L = 16;
    int tc = tcnt[qi]; if (tc > 16) tc = 16;
    const int need = 16 - L;
    for (int r = 0; r < need; ++r){
      int best = 0x7FFFFFFF, bj = -1;
      for (int j = 0; j < tc; ++j){
        const int v = tiebuf[qi*16+j];
        if (v < best){ best = v; bj = j; }
      }
      if (bj >= 0){ tiebuf[qi*16+bj] = 0x7FFFFFFF; orow[L+r] = best; }
      else orow[L+r] = n;
    }
  }
}

// ---------------- generic 128x128 bf16 GEMM: C[m][n] = sum_k A[m][k]*B[n][k] (+bias) ----------------
__global__ __launch_bounds__(256,2) void gemm128_k(
    const u16* __restrict__ A, const int lda,
    const u16* __restrict__ Bw, const int ldb,
    u16* __restrict__ C, const int ldc,
    const int K, const float* __restrict__ bias,
    const size_t zA, const size_t zC){
  __shared__ __attribute__((aligned(16))) u16 As[128*32];
  __shared__ __attribute__((aligned(16))) u16 Bs[128*32];
  A += blockIdx.z * zA;
  C += blockIdx.z * zC;
  const int tid = threadIdx.x, lane = tid & 63, w = tid >> 6;
  const int mrow = lane & 15, quad = lane >> 4;
  const size_t mbase = (size_t)blockIdx.x*128, nbase = (size_t)blockIdx.y*128;
  const int wr = (w&1)*64, wc = (w>>1)*64;
  f32x4 acc[4][4];
  #pragma unroll
  for (int i=0;i<4;++i)
    #pragma unroll
    for (int j=0;j<4;++j)
      #pragma unroll
      for (int r=0;r<4;++r) acc[i][j][r] = 0.f;
  const int sr = tid >> 2, sk = (tid & 3)*8;
  u16* lA0 = &As[w*512]; u16* lA1 = &As[2048 + w*512];
  u16* lB0 = &Bs[w*512]; u16* lB1 = &Bs[2048 + w*512];
  for (int k0 = 0; k0 < K; k0 += 32){
    __syncthreads();
    async_copy16(A  + (mbase      + sr)*(size_t)lda + k0 + sk, lA0);
    async_copy16(A  + (mbase + 64 + sr)*(size_t)lda + k0 + sk, lA1);
    async_copy16(Bw + (nbase      + sr)*(size_t)ldb + k0 + sk, lB0);
    async_copy16(Bw + (nbase + 64 + sr)*(size_t)ldb + k0 + sk, lB1);
    __syncthreads();
    bf16x8 af[4], bf[4];
    #pragma unroll
    for (int rt=0;rt<4;++rt) af[rt] = *(const bf16x8*)&As[(wr+rt*16+mrow)*32 + quad*8];
    #pragma unroll
    for (int ct=0;ct<4;++ct) bf[ct] = *(const bf16x8*)&Bs[(wc+ct*16+mrow)*32 + quad*8];
    #pragma unroll
    for (int rt=0;rt<4;++rt)
      #pragma unroll
      for (int ct=0;ct<4;++ct) acc[rt][ct] = MFMA16(af[rt], bf[ct], acc[rt][ct]);
  }
  #pragma unroll
  for (int rt=0;rt<4;++rt)
    #pragma unroll
    for (int ct=0;ct<4;++ct){
      const size_t row0 = mbase + wr + rt*16 + quad*4;
      const int col = (int)nbase + wc + ct*16 + mrow;
      const float bv = bias ? bias[col] : 0.f;
      #pragma unroll
      for (int r=0;r<4;++r) C[(row0+r)*(size_t)ldc + col] = f2b(acc[rt][ct][r] + bv);
    }
}

// ---------------- fused GEMM(K=256, N=256) + row LayerNorm: C = ln(A @ B.T)*g+b ----------------
__global__ __launch_bounds__(512,4) void gemmln_k(
    const u16* __restrict__ A, const int lda, const size_t zA,
    const u16* __restrict__ Bw, const size_t zB,
    u16* __restrict__ C, const int ldc, const int zCcol,
    const float* __restrict__ g, const float* __restrict__ bta){
  __shared__ __attribute__((aligned(16))) u16 As[128*32];
  __shared__ __attribute__((aligned(16))) u16 Bs[256*32];
  __shared__ float sS[128], sSS[128];
  A  += blockIdx.z * zA;
  Bw += blockIdx.z * zB;
  const int ccol0 = (int)blockIdx.z * zCcol;
  const int tid = threadIdx.x, lane = tid & 63, w = tid >> 6;
  const int mrow = lane & 15, quad = lane >> 4;
  const size_t mbase = (size_t)blockIdx.x*128;
  const int wr = (w&1)*64, wc = (w>>1)*64;
  if (tid < 128){ sS[tid] = 0.f; sSS[tid] = 0.f; }
  f32x4 acc[4][4];
  #pragma unroll
  for (int i=0;i<4;++i)
    #pragma unroll
    for (int j=0;j<4;++j)
      #pragma unroll
      for (int r=0;r<4;++r) acc[i][j][r] = 0.f;
  const int sr = tid >> 2, sk = (tid & 3)*8;
  u16* ldA  = &As[w*512];
  u16* ldB0 = &Bs[w*512];
  u16* ldB1 = &Bs[4096 + w*512];
  for (int k0 = 0; k0 < 256; k0 += 32){
    __syncthreads();
    async_copy16(A  + (mbase + sr)*(size_t)lda + k0 + sk, ldA);
    async_copy16(Bw + (size_t)sr*256        + k0 + sk, ldB0);
    async_copy16(Bw + (size_t)(128+sr)*256  + k0 + sk, ldB1);
    __syncthreads();
    bf16x8 af[4], bf[4];
    #pragma unroll
    for (int rt=0;rt<4;++rt) af[rt] = *(const bf16x8*)&As[(wr+rt*16+mrow)*32 + quad*8];
    #pragma unroll
    for (int ct=0;ct<4;++ct) bf[ct] = *(const bf16x8*)&Bs[(wc+ct*16+mrow)*32 + quad*8];
    #pragma unroll
    for (int rt=0;rt<4;++rt)
      #pragma unroll
      for (int ct=0;ct<4;++ct) acc[rt][ct] = MFMA16(af[rt], bf[ct], acc[rt][ct]);
  }
  #pragma unroll
  for (int rt=0;rt<4;++rt)
    #pragma unroll
    for (int r=0;r<4;++r){
      float s  = acc[rt][0][r]+acc[rt][1][r]+acc[rt][2][r]+acc[rt][3][r];
      float ss = acc[rt][0][r]*acc[rt][0][r]+acc[rt][1][r]*acc[rt][1][r]
               + acc[rt][2][r]*acc[rt][2][r]+acc[rt][3][r]*acc[rt][3][r];
      s  = rowsum16(s);
      ss = rowsum16(ss);
      if (mrow == 0){
        const int row = wr + rt*16 + quad*4 + r;
        atomicAdd(&sS[row],  s);
        atomicAdd(&sSS[row], ss);
      }
    }
  __syncthreads();
  #pragma unroll
  for (int ct=0;ct<4;++ct){
    const int col = wc + ct*16 + mrow;
    const float gv = g[col], bv = bta[col];
    #pragma unroll
    for (int rt=0;rt<4;++rt)
      #pragma unroll
      for (int r=0;r<4;++r){
        const int row = wr + rt*16 + quad*4 + r;
        const float mu = sS[row]*(1.f/256.f);
        const float var = sSS[row]*(1.f/256.f) - mu*mu;
        const float rs = rsqrtf(var + 1e-5f);
        C[(mbase+row)*(size_t)ldc + ccol0 + col] = f2b((acc[rt][ct][r]-mu)*rs*gv + bv);
      }
  }
}

// ---------------- fused per-neighbor attention kernel (v13 = v12 + LDS v-gather) ----------------
// block = 64 rows (4 queries x 16), 512 threads = 8 waves, wave w owns f-slice [w*32,w*32+32).
// Merged G1+G2a k-loop; after the h2 barrier h1buf is dead -> stage all 64 v rows there with
// coalesced uint4 loads (latency hidden by G2b), read v from LDS in the softmax.
#define DP   264
#define RELP 40
__global__ __launch_bounds__(512,4) void attn_k(
    const float* __restrict__ xyz, const int* __restrict__ idxb,
    const u16* __restrict__ lnqkv, const u16* __restrict__ qa, const u16* __restrict__ ka,
    const u16* __restrict__ mcomb, const u16* __restrict__ wp2, const u16* __restrict__ wa2,
    const u16* __restrict__ wp1pk, u16* __restrict__ res){
  __shared__ __attribute__((aligned(16))) u16 h1buf[64*DP];   // h1, later v rows
  __shared__ __attribute__((aligned(16))) u16 h2buf[64*DP];
  __shared__ __attribute__((aligned(16))) u16 srel[64*RELP];
  __shared__ int sidx[64];
  const int tid = threadIdx.x;
  const int b = blockIdx.x >> 10;
  const int nbase = (blockIdx.x & 1023) << 2;
  const size_t gb = (size_t)b << 12;
  if (tid < 64){
    const int m = tid;
    const int im = idxb[(gb + nbase + (m>>4))*16 + (m&15)] & 4095;
    sidx[m] = im;
    const int nn = nbase + (m>>4);
    const float* pq = xyz + (gb+nn)*3;
    const float* pm = xyz + (gb+im)*3;
    const float rx = pq[0]-pm[0], ry = pq[1]-pm[1], rz = pq[2]-pm[2];
    uint4 a; a.x = pk2f(rx,ry); a.y = pk2f(rz,0.f); a.z = 0u; a.w = 0u;
    uint4 z; z.x = z.y = z.z = z.w = 0u;
    *(uint4*)&srel[m*RELP]    = a;
    *(uint4*)&srel[m*RELP+8]  = z;
    *(uint4*)&srel[m*RELP+16] = z;
    *(uint4*)&srel[m*RELP+24] = z;
  }
  __syncthreads();
  const int lane = tid & 63, w = tid >> 6;
  const int mrow = lane & 15, quad = lane >> 4;
  const int fr = w << 5;
  {
    bf16x8 aW[2], bR[4];
    #pragma unroll
    for (int ht=0;ht<2;++ht) aW[ht] = *(const bf16x8*)&wp1pk[(fr+ht*16+mrow)*32 + quad*8];
    #pragma unroll
    for (int mt=0;mt<4;++mt) bR[mt] = *(const bf16x8*)&srel[(mt*16+mrow)*RELP + quad*8];
    #pragma unroll
    for (int ht=0;ht<2;++ht)
      #pragma unroll
      for (int mt=0;mt<4;++mt){
        f32x4 hz;
        #pragma unroll
        for (int r=0;r<4;++r) hz[r]=0.f;
        hz = MFMA16(aW[ht], bR[mt], hz);
        float h0 = hz[0]>0.f?hz[0]:0.f, h1v = hz[1]>0.f?hz[1]:0.f;
        float h2v = hz[2]>0.f?hz[2]:0.f, h3 = hz[3]>0.f?hz[3]:0.f;
        uint2 o; o.x = pk2f(h0,h1v); o.y = pk2f(h2v,h3);
        *(uint2*)&h1buf[(mt*16+mrow)*DP + fr + ht*16 + quad*4] = o;
      }
  }
  int midx[4];
  #pragma unroll
  for (int mt = 0; mt < 4; ++mt) midx[mt] = sidx[mt*16 + mrow];
  __syncthreads();
  // merged G1+G2a: at (D[f][m]) and av (flipped D[m][g]) from shared bH
  f32x4 at[2][4], av[2][4];
  #pragma unroll
  for (int i=0;i<2;++i)
    #pragma unroll
    for (int j=0;j<4;++j)
      #pragma unroll
      for (int r=0;r<4;++r){ at[i][j][r]=0.f; av[i][j][r]=0.f; }
  #pragma unroll 1
  for (int ks = 0; ks < 8; ++ks){
    const int koff = ks*32 + quad*8;
    bf16x8 aM[2], aP[2], bH[4];
    #pragma unroll
    for (int ft=0;ft<2;++ft){
      aM[ft] = *(const bf16x8*)&mcomb[(fr+ft*16+mrow)*256 + koff];
      aP[ft] = *(const bf16x8*)&wp2  [(fr+ft*16+mrow)*256 + koff];
    }
    #pragma unroll
    for (int mt=0;mt<4;++mt) bH[mt] = *(const bf16x8*)&h1buf[(mt*16+mrow)*DP + koff];
    #pragma unroll
    for (int ft=0;ft<2;++ft)
      #pragma unroll
      for (int mt=0;mt<4;++mt){
        at[ft][mt] = MFMA16(aM[ft], bH[mt], at[ft][mt]);
        av[ft][mt] = MFMA16(bH[mt], aP[ft], av[ft][mt]);
      }
  }
  uint2 qkp[2][4];
  #pragma unroll
  for (int ft = 0; ft < 2; ++ft)
    #pragma unroll
    for (int mt = 0; mt < 4; ++mt){
      const int f = fr + ft*16 + quad*4;
      const uint2 uq = *(const uint2*)&qa[(gb + nbase + mt)*256 + f];
      const uint2 uk = *(const uint2*)&ka[(gb + (size_t)midx[mt])*256 + f];
      uint2 o;
      o.x = pk2f(b2f(uq.x&0xffff)-b2f(uk.x&0xffff), b2f(uq.x>>16)-b2f(uk.x>>16));
      o.y = pk2f(b2f(uq.y&0xffff)-b2f(uk.y&0xffff), b2f(uq.y>>16)-b2f(uk.y>>16));
      qkp[ft][mt] = o;
    }
  #pragma unroll
  for (int ft=0;ft<2;++ft)
    #pragma unroll
    for (int mt=0;mt<4;++mt){
      const int moff = (mt*16+mrow)*DP + fr + ft*16 + quad*4;
      const uint2 qv = qkp[ft][mt];
      float t0 = at[ft][mt][0] + b2f(qv.x&0xffff);
      float t1 = at[ft][mt][1] + b2f(qv.x>>16);
      float t2 = at[ft][mt][2] + b2f(qv.y&0xffff);
      float t3 = at[ft][mt][3] + b2f(qv.y>>16);
      t0 = t0>0.f?t0:0.f; t1 = t1>0.f?t1:0.f; t2 = t2>0.f?t2:0.f; t3 = t3>0.f?t3:0.f;
      uint2 o; o.x = pk2f(t0,t1); o.y = pk2f(t2,t3);
      *(uint2*)&h2buf[moff] = o;
    }
  __syncthreads();             // h2 complete; h1buf now dead
  // ---- stage v rows into h1buf (coalesced): thread t -> row t>>3, 4 x uint4 chunks
  {
    const int vrow = tid >> 3, c8 = tid & 7;
    const u16* src = lnqkv + (gb + (size_t)sidx[vrow])*768 + 512;
    u16* dst = &h1buf[vrow*DP];
    #pragma unroll
    for (int i = 0; i < 4; ++i){
      const int e = (c8 + 8*i)*8;
      *(uint4*)&dst[e] = *(const uint4*)&src[e];
    }
  }
  // G2b: al = h2 @ Wa2.T  FLIPPED: D[m][g]  (hides the v-load latency)
  f32x4 al[2][4];
  #pragma unroll
  for (int i=0;i<2;++i)
    #pragma unroll
    for (int j=0;j<4;++j)
      #pragma unroll
      for (int r=0;r<4;++r) al[i][j][r]=0.f;
  #pragma unroll 2
  for (int ks = 0; ks < 8; ++ks){
    const int koff = ks*32 + quad*8;
    bf16x8 aW[2], bH[4];
    #pragma unroll
    for (int gt=0;gt<2;++gt) aW[gt] = *(const bf16x8*)&wa2[(fr+gt*16+mrow)*256 + koff];
    #pragma unroll
    for (int mt=0;mt<4;++mt) bH[mt] = *(const bf16x8*)&h2buf[(mt*16+mrow)*DP + koff];
    #pragma unroll
    for (int gt=0;gt<2;++gt)
      #pragma unroll
      for (int mt=0;mt<4;++mt) al[gt][mt] = MFMA16(bH[mt], aW[gt], al[gt][mt]);
  }
  __syncthreads();             // v rows staged
  // softmax over k = quad*4+reg (in-lane + cross-quad); v from LDS
  const float sc = 0.0901684f;   // log2(e)/sqrt(256)
  #pragma unroll
  for (int gt=0;gt<2;++gt)
    #pragma unroll
    for (int mt=0;mt<4;++mt){
      float prs = 0.f, wgs = 0.f;
      #pragma unroll
      for (int r=0;r<4;++r){
        const int vr = mt*16 + quad*4 + r;
        const float val = av[gt][mt][r] + b2f((u32)h1buf[vr*DP + fr + gt*16 + mrow]);
        const float pr = exp2f(al[gt][mt][r]*sc);
        prs += pr;
        wgs += pr*val;
      }
      prs += __shfl_xor(prs, 16, 64); prs += __shfl_xor(prs, 32, 64);
      wgs += __shfl_xor(wgs, 16, 64); wgs += __shfl_xor(wgs, 32, 64);
      const float rv = wgs * __builtin_amdgcn_rcpf(prs);
      if (quad == 0)
        res[(gb + nbase + mt)*256 + fr + gt*16 + mrow] = f2b(rv);
    }
}

// ---------------- final: out = ln(r1 @ W_post.T + b_post)*g+b + features ----------------
__global__ __launch_bounds__(256,2) void d2_k(
    const u16* __restrict__ r1, const u16* __restrict__ wpost,
    const float* __restrict__ bpost, const float* __restrict__ g, const float* __restrict__ bt,
    const float* __restrict__ feat, float* __restrict__ out){
  const int tid = threadIdx.x, lane = tid & 63, w = tid >> 6;
  const int mrow = lane & 15, quad = lane >> 4;
  const size_t rb = (size_t)blockIdx.x*128 + w*32;
  f32x4 acc[2][4];
  #pragma unroll
  for (int i=0;i<2;++i)
    #pragma unroll
    for (int j=0;j<4;++j)
      #pragma unroll
      for (int r=0;r<4;++r) acc[i][j][r]=0.f;
  #pragma unroll 1
  for (int ks = 0; ks < 8; ++ks){
    const int koff = ks*32 + quad*8;
    bf16x8 af[2], bf[4];
    #pragma unroll
    for (int rt=0;rt<2;++rt) af[rt] = *(const bf16x8*)&r1[(rb+rt*16+mrow)*256 + koff];
    #pragma unroll
    for (int ct=0;ct<4;++ct) bf[ct] = *(const bf16x8*)&wpost[(ct*16+mrow)*256 + koff];
    #pragma unroll
    for (int rt=0;rt<2;++rt)
      #pragma unroll
      for (int ct=0;ct<4;++ct) acc[rt][ct] = MFMA16(af[rt], bf[ct], acc[rt][ct]);
  }
  #pragma unroll
  for (int ct=0;ct<4;++ct){
    const float bv = bpost[ct*16+mrow];
    #pragma unroll
    for (int rt=0;rt<2;++rt)
      #pragma unroll
      for (int r=0;r<4;++r) acc[rt][ct][r] += bv;
  }
  #pragma unroll
  for (int rt=0;rt<2;++rt)
    #pragma unroll
    for (int r=0;r<4;++r){
      float s  = acc[rt][0][r]+acc[rt][1][r]+acc[rt][2][r]+acc[rt][3][r];
      float ss = acc[rt][0][r]*acc[rt][0][r]+acc[rt][1][r]*acc[rt][1][r]
               + acc[rt][2][r]*acc[rt][2][r]+acc[rt][3][r]*acc[rt][3][r];
      s  = rowsum16(s);
      ss = rowsum16(ss);
      const float mu = s*(1.f/64.f);
      const float var = ss*(1.f/64.f) - mu*mu;
      const float rs = rsqrtf(var + 1e-5f);
      const size_t row = rb + rt*16 + quad*4 + r;
      #pragma unroll
      for (int ct=0;ct<4;++ct){
        const int n = ct*16 + mrow;
        out[row*64 + n] = (acc[rt][ct][r]-mu)*rs*g[n] + bt[n] + feat[row*64 + n];
      }
    }
}

// ---------------- launcher ----------------
extern "C" void kernel_launch(void* const* d_in, const int* in_sizes, int n_in,
                              void* d_out, int out_size, void* d_ws, size_t ws_size,
                              hipStream_t stream){
  const float* xyz    = (const float*)d_in[0];
  const float* feat   = (const float*)d_in[1];
  const float* W_pre  = (const float*)d_in[2];
  const float* b_pre  = (const float*)d_in[3];
  const float* W_post = (const float*)d_in[4];
  const float* b_post = (const float*)d_in[5];
  const float* Wp1    = (const float*)d_in[6];
  const float* Wp2    = (const float*)d_in[7];
  const float* Wa1    = (const float*)d_in[8];
  const float* Wa2    = (const float*)d_in[9];
  const float* WQ     = (const float*)d_in[10];
  const float* WK     = (const float*)d_in[11];
  const float* WV     = (const float*)d_in[12];
  const float* Wproj  = (const float*)d_in[13];
  const float* g_dm   = (const float*)d_in[14];
  const float* b_dm   = (const float*)d_in[15];
  const float* g_dp   = (const float*)d_in[16];
  const float* b_dp   = (const float*)d_in[17];
  float* out = (float*)d_out;
  if (ws_size < WS_NEED) return;
  char* ws = (char*)d_ws;
  int* idxw   = (int*)(ws + OFF_IDX);
  u16* featb  = (u16*)(ws + OFF_FEATB);
  u16* wpreb  = (u16*)(ws + OFF_WPRE);
  u16* wqkvb  = (u16*)(ws + OFF_WQKV);
  u16* wa1b   = (u16*)(ws + OFF_WA1);
  u16* wa2b   = (u16*)(ws + OFF_WA2);
  u16* wp2b   = (u16*)(ws + OFF_WP2);
  u16* wprojb = (u16*)(ws + OFF_WPROJ);
  u16* wpostb = (u16*)(ws + OFF_WPOST);
  u16* mcombb = (u16*)(ws + OFF_MCOMB);
  u16* inp    = (u16*)(ws + OFF_INP);
  u16* lnqkv  = (u16*)(ws + OFF_LNQKV);
  u16* qab    = (u16*)(ws + OFF_QA);
  u16* kab    = (u16*)(ws + OFF_KA);
  u16* resb   = (u16*)(ws + OFF_RES);
  u16* r1b    = (u16*)(ws + OFF_R1);
  u16* wp1pk  = (u16*)(ws + OFF_WP1PK);
  u16* wp2T   = (u16*)(ws + OFF_WP2T);

  convert_k<<<6081,256,0,stream>>>(feat,W_pre,WQ,WK,WV,Wa1,Wa2,Wp2,Wproj,W_post,Wp1,
                                   featb,wpreb,wqkvb,wa1b,wa2b,wp2b,wprojb,wpostb,
                                   wp1pk,wp2T);
  gemm128_k<<<dim3(2,2),256,0,stream>>>(wa1b,256, wp2T,256, mcombb,256, 256, nullptr, 0,0);
  knn_kernel<<<1024,256,0,stream>>>(xyz,idxw);
  gemm128_k<<<dim3(128,2),256,0,stream>>>(featb,64,  wpreb,64,  inp,256, 64,  b_pre, 0,0);
  gemmln_k<<<dim3(128,1,3),512,0,stream>>>(inp,256,0, wqkvb,65536, lnqkv,768,256, g_dm,b_dm);
  gemm128_k<<<dim3(128,2,2),256,0,stream>>>(lnqkv,768, wa1b,256, qab,256, 256, nullptr,
                                            256, 4194304);
  attn_k<<<4096,512,0,stream>>>(xyz,idxw,lnqkv,qab,kab,mcombb,wp2b,wa2b,wp1pk,resb);
  gemmln_k<<<dim3(128,1,1),512,0,stream>>>(resb,256,0, wprojb,0, r1b,256,0, g_dm,b_dm);
  d2_k<<<128,256,0,stream>>>(r1b,wpostb,b_post,g_dp,b_dp,feat,out);
}

// Round 15
// 524.877 us; speedup vs baseline: 1.0293x; 1.0293x over previous
//
#include <hip/hip_runtime.h>
#include <hip/hip_bf16.h>

typedef unsigned short u16;
typedef unsigned int   u32;
typedef __attribute__((ext_vector_type(8))) short bf16x8;
typedef __attribute__((ext_vector_type(4))) float f32x4;

#define MFMA16(a,b,c) __builtin_amdgcn_mfma_f32_16x16x32_bf16((a),(b),(c),0,0,0)

__device__ __forceinline__ float b2f(u32 h){ return __uint_as_float(h<<16); }
__device__ __forceinline__ u16 f2b(float f){
  u32 u = __float_as_uint(f);
  return (u16)((u + 0x7FFFu + ((u>>16)&1u))>>16);
}
// HW packed convert: v_cvt_pk_bf16_f32 (RNE)
__device__ __forceinline__ u32 pk2f(float a,float b){
  __hip_bfloat162 h = __float22bfloat162_rn(float2{a,b});
  return *reinterpret_cast<u32*>(&h);
}
__device__ __forceinline__ u32 umin32(u32 a,u32 b){ return a<b?a:b; }
__device__ __forceinline__ u32 umax32(u32 a,u32 b){ return a>b?a:b; }

// 16-lane row-sum on the VALU pipe via DPP row_ror
template<int CTRL>
__device__ __forceinline__ float dpp_add(float x){
  int t = __builtin_amdgcn_update_dpp(0, __float_as_int(x), CTRL, 0xF, 0xF, true);
  return x + __int_as_float(t);
}
__device__ __forceinline__ float rowsum16(float x){
  x = dpp_add<0x121>(x);
  x = dpp_add<0x122>(x);
  x = dpp_add<0x124>(x);
  x = dpp_add<0x128>(x);
  return x;
}

__device__ __forceinline__ void async_copy16(const void* g, void* l){
  __builtin_amdgcn_global_load_lds((const __attribute__((address_space(1))) u32*)g,
                                   (__attribute__((address_space(3))) u32*)l, 16, 0, 0);
}

// ---------------- workspace layout (bytes) ----------------
#define OFF_IDX    0ull
#define OFF_WQKV   3178496ull
#define OFF_WA1    3571712ull
#define OFF_WA2    3702784ull
#define OFF_WP2    3833856ull
#define OFF_WPROJ  3964928ull
#define OFF_WPOST  4096000ull
#define OFF_MCOMB  4128768ull
#define OFF_INP    4259840ull
#define OFF_LNQKV  37814272ull
#define OFF_QA     62980096ull
#define OFF_KA     71368704ull
#define OFF_RES    79757312ull
#define OFF_D1     88145920ull
#define OFF_R1     96534528ull
#define WS_NEED    104923136ull
#define OFF_WP1PK  OFF_D1

// ---------------- fused prologue: weight converts + wp1 pack + mcomb + kNN + inp GEMM ----------------
// all paths independent; dispatched by blockIdx range.
__device__ __forceinline__ void ins16(u32 (&a)[16], u32 key){
  #pragma unroll
  for (int j = 15; j >= 1; --j) a[j] = umin32(umax32(a[j-1],key), a[j]);
  a[0] = umin32(a[0], key);
}

__device__ __forceinline__ float dist2(float ax,float ay,float az,float bx,float by,float bz){
  const float dx = ax-bx, dy = ay-by, dz = az-bz;
  return __fmaf_rn(dx,dx, __fmaf_rn(dy,dy, dz*dz));
}

__global__ __launch_bounds__(256,2) void prep_k(
    const float* __restrict__ xyz, const float* __restrict__ feat,
    const float* __restrict__ wpre, const float* __restrict__ bpre,
    const float* __restrict__ wq, const float* __restrict__ wk, const float* __restrict__ wv,
    const float* __restrict__ wa1, const float* __restrict__ wa2, const float* __restrict__ wp2,
    const float* __restrict__ wproj, const float* __restrict__ wpost,
    const float* __restrict__ wp1,
    u16* __restrict__ dwqkv, u16* __restrict__ dwa1, u16* __restrict__ dwa2,
    u16* __restrict__ dwp2, u16* __restrict__ dwproj, u16* __restrict__ dwpost,
    u16* __restrict__ dwp1pk, u16* __restrict__ dmcomb,
    int* __restrict__ idxout, u16* __restrict__ dinp){
  __shared__ __attribute__((aligned(16))) char smem[50464];
  const int bid = blockIdx.x, tid = threadIdx.x;
  if (bid < 1856){
    // ---- weight f32->bf16 converts
    int id = bid*256 + tid;
    const float* s; u16* d; int off;
    if      (id <  65536){ s=wq;    d=dwqkv;        off=id; }
    else if (id < 131072){ s=wk;    d=dwqkv+65536;  off=id-65536; }
    else if (id < 196608){ s=wv;    d=dwqkv+131072; off=id-131072; }
    else if (id < 262144){ s=wa1;   d=dwa1;         off=id-196608; }
    else if (id < 327680){ s=wa2;   d=dwa2;         off=id-262144; }
    else if (id < 393216){ s=wp2;   d=dwp2;         off=id-327680; }
    else if (id < 458752){ s=wproj; d=dwproj;       off=id-393216; }
    else                 { s=wpost; d=dwpost;       off=id-458752; }
    d[off] = f2b(s[off]);
  } else if (bid == 1856){
    // ---- Wp1 packed for MFMA A-operand: [256 h][32 k]
    const int h = tid;
    const float w0 = wp1[h*3], w1 = wp1[h*3+1], w2 = wp1[h*3+2];
    uint4 a; a.x = pk2f(w0,w1); a.y = pk2f(w2,0.f); a.z = 0u; a.w = 0u;
    uint4 z; z.x = z.y = z.z = z.w = 0u;
    *(uint4*)&dwp1pk[h*32]    = a;
    *(uint4*)&dwp1pk[h*32+8]  = z;
    *(uint4*)&dwp1pk[h*32+16] = z;
    *(uint4*)&dwp1pk[h*32+24] = z;
  } else if (bid < 2113){
    // ---- Mcomb = Wa1 @ Wp2 (f32 accumulate, one row per block)
    const int f = bid - 1857, h = tid;
    float acc = 0.f;
    #pragma unroll 4
    for (int j = 0; j < 256; ++j) acc = __fmaf_rn(wa1[f*256+j], wp2[j*256+h], acc);
    dmcomb[f*256+h] = f2b(acc);
  } else if (bid < 3137){
    // ---- kNN: exact top-16
    float* sx = (float*)smem; float* sy = sx + 4104; float* sz = sx + 8208;
    int* lcnt   = (int*)(smem + 49248);
    int* tcnt   = (int*)(smem + 49312);
    u32* tbuf   = (u32*)(smem + 49376);
    int* tiebuf = (int*)(smem + 49440);
    const int tb = bid - 2113;
    const int b  = tb >> 8;
    const int n0 = (tb & 255) << 4;
    const float* base = xyz + (size_t)b*12288;
    #pragma unroll
    for (int i = 0; i < 12; ++i){
      const float4 v = *(const float4*)(base + tid*48 + i*4);
      const float vv[4] = {v.x, v.y, v.z, v.w};
      #pragma unroll
      for (int j = 0; j < 4; ++j){
        const int e = i*4 + j;
        const int c = e % 3;
        const int m = tid*16 + e/3;
        float* arr = (c==0)?sx:((c==1)?sy:sz);
        arr[m + (m>>9)] = vv[j];
      }
    }
    if (tid < 16){ lcnt[tid] = 0; tcnt[tid] = 0; }
    __syncthreads();
    const int qi = tid >> 4, p = tid & 15;
    const int n = n0 + qi;
    const int sn = n + (n>>9);
    const float qx = sx[sn], qy = sy[sn], qz = sz[sn];
    u32 a[16];
    #pragma unroll
    for (int j = 0; j < 16; ++j) a[j] = 0xFFFFFFFFu;
    const int sb = p*256 + (p>>1);
    #pragma unroll 2
    for (int i = 0; i < 256; ++i){
      const float d2 = dist2(sx[sb+i],sy[sb+i],sz[sb+i],qx,qy,qz);
      ins16(a, __float_as_uint(d2));
    }
    #pragma unroll
    for (int s = 8; s >= 1; s >>= 1){
      u32 o[16];
      #pragma unroll
      for (int j = 0; j < 16; ++j) o[j] = __shfl_down(a[j], (unsigned)s, 64);
      if (p < s){
        #pragma unroll
        for (int j = 0; j < 16; ++j) ins16(a, o[j]);
      }
    }
    if (p == 0) tbuf[qi] = a[15];
    __syncthreads();
    const u32 T = tbuf[qi];
    int* orow = idxout + ((size_t)(b<<12)+n)*16;
    const int gbase = p*256;
    for (int i = 0; i < 256; ++i){
      const float d2 = dist2(sx[sb+i],sy[sb+i],sz[sb+i],qx,qy,qz);
      const u32 kb = __float_as_uint(d2);
      if (kb < T){
        const int pos = atomicAdd(&lcnt[qi],1);
        if (pos < 16) orow[pos] = gbase + i;
      } else if (kb == T){
        const int t = atomicAdd(&tcnt[qi],1);
        if (t < 16) tiebuf[qi*16+t] = gbase + i;
      }
    }
    __syncthreads();
    if (p == 0){
      int L = lcnt[qi]; if (L > 16) L = 16;
      int tc = tcnt[qi]; if (tc > 16) tc = 16;
      const int need = 16 - L;
      for (int r = 0; r < need; ++r){
        int best = 0x7FFFFFFF, bj = -1;
        for (int j = 0; j < tc; ++j){
          const int v = tiebuf[qi*16+j];
          if (v < best){ best = v; bj = j; }
        }
        if (bj >= 0){ tiebuf[qi*16+bj] = 0x7FFFFFFF; orow[L+r] = best; }
        else orow[L+r] = n;
      }
    }
  } else {
    // ---- inp = feat @ W_pre.T + b_pre (K=64), 128x128 tile, in-kernel f32->bf16 staging
    u16* As = (u16*)smem;            // [128][72] padded
    u16* Bs = (u16*)smem + 9216;     // [128][72]
    const int tb = bid - 3137;
    const int mb = tb >> 1, nb = tb & 1;
    #pragma unroll
    for (int i = 0; i < 32; ++i){
      const int e = i*256 + tid;     // 0..8191
      const int row = e >> 6, k = e & 63;
      As[row*72+k] = f2b(feat[(size_t)(mb*128)*64 + e]);
      Bs[row*72+k] = f2b(wpre[(size_t)(nb*128)*64 + e]);
    }
    __syncthreads();
    const int lane = tid & 63, w = tid >> 6;
    const int mrow = lane & 15, quad = lane >> 4;
    const int wr = (w&1)*64, wc = (w>>1)*64;
    f32x4 acc[4][4];
    #pragma unroll
    for (int i=0;i<4;++i)
      #pragma unroll
      for (int j=0;j<4;++j)
        #pragma unroll
        for (int r=0;r<4;++r) acc[i][j][r] = 0.f;
    #pragma unroll
    for (int ks = 0; ks < 2; ++ks){
      const int koff = ks*32 + quad*8;
      bf16x8 af[4], bf[4];
      #pragma unroll
      for (int rt=0;rt<4;++rt) af[rt] = *(const bf16x8*)&As[(wr+rt*16+mrow)*72 + koff];
      #pragma unroll
      for (int ct=0;ct<4;++ct) bf[ct] = *(const bf16x8*)&Bs[(wc+ct*16+mrow)*72 + koff];
      #pragma unroll
      for (int rt=0;rt<4;++rt)
        #pragma unroll
        for (int ct=0;ct<4;++ct) acc[rt][ct] = MFMA16(af[rt], bf[ct], acc[rt][ct]);
    }
    #pragma unroll
    for (int rt=0;rt<4;++rt)
      #pragma unroll
      for (int ct=0;ct<4;++ct){
        const size_t row0 = (size_t)mb*128 + wr + rt*16 + quad*4;
        const int col = nb*128 + wc + ct*16 + mrow;
        const float bv = bpre[col];
        #pragma unroll
        for (int r=0;r<4;++r) dinp[(row0+r)*256 + col] = f2b(acc[rt][ct][r] + bv);
      }
  }
}

// ---------------- generic 128x128 bf16 GEMM: C[m][n] = sum_k A[m][k]*B[n][k] ----------------
__global__ __launch_bounds__(256,2) void gemm128_k(
    const u16* __restrict__ A, const int lda,
    const u16* __restrict__ Bw, const int ldb,
    u16* __restrict__ C, const int ldc,
    const int K, const float* __restrict__ bias,
    const size_t zA, const size_t zC){
  __shared__ __attribute__((aligned(16))) u16 As[128*32];
  __shared__ __attribute__((aligned(16))) u16 Bs[128*32];
  A += blockIdx.z * zA;
  C += blockIdx.z * zC;
  const int tid = threadIdx.x, lane = tid & 63, w = tid >> 6;
  const int mrow = lane & 15, quad = lane >> 4;
  const size_t mbase = (size_t)blockIdx.x*128, nbase = (size_t)blockIdx.y*128;
  const int wr = (w&1)*64, wc = (w>>1)*64;
  f32x4 acc[4][4];
  #pragma unroll
  for (int i=0;i<4;++i)
    #pragma unroll
    for (int j=0;j<4;++j)
      #pragma unroll
      for (int r=0;r<4;++r) acc[i][j][r] = 0.f;
  const int sr = tid >> 2, sk = (tid & 3)*8;
  u16* lA0 = &As[w*512]; u16* lA1 = &As[2048 + w*512];
  u16* lB0 = &Bs[w*512]; u16* lB1 = &Bs[2048 + w*512];
  for (int k0 = 0; k0 < K; k0 += 32){
    __syncthreads();
    async_copy16(A  + (mbase      + sr)*(size_t)lda + k0 + sk, lA0);
    async_copy16(A  + (mbase + 64 + sr)*(size_t)lda + k0 + sk, lA1);
    async_copy16(Bw + (nbase      + sr)*(size_t)ldb + k0 + sk, lB0);
    async_copy16(Bw + (nbase + 64 + sr)*(size_t)ldb + k0 + sk, lB1);
    __syncthreads();
    bf16x8 af[4], bf[4];
    #pragma unroll
    for (int rt=0;rt<4;++rt) af[rt] = *(const bf16x8*)&As[(wr+rt*16+mrow)*32 + quad*8];
    #pragma unroll
    for (int ct=0;ct<4;++ct) bf[ct] = *(const bf16x8*)&Bs[(wc+ct*16+mrow)*32 + quad*8];
    #pragma unroll
    for (int rt=0;rt<4;++rt)
      #pragma unroll
      for (int ct=0;ct<4;++ct) acc[rt][ct] = MFMA16(af[rt], bf[ct], acc[rt][ct]);
  }
  #pragma unroll
  for (int rt=0;rt<4;++rt)
    #pragma unroll
    for (int ct=0;ct<4;++ct){
      const size_t row0 = mbase + wr + rt*16 + quad*4;
      const int col = (int)nbase + wc + ct*16 + mrow;
      const float bv = bias ? bias[col] : 0.f;
      #pragma unroll
      for (int r=0;r<4;++r) C[(row0+r)*(size_t)ldc + col] = f2b(acc[rt][ct][r] + bv);
    }
}

// ---------------- fused GEMM(K=256, N=256) + row LayerNorm: C = ln(A @ B.T)*g+b ----------------
__global__ __launch_bounds__(512,4) void gemmln_k(
    const u16* __restrict__ A, const int lda, const size_t zA,
    const u16* __restrict__ Bw, const size_t zB,
    u16* __restrict__ C, const int ldc, const int zCcol,
    const float* __restrict__ g, const float* __restrict__ bta){
  __shared__ __attribute__((aligned(16))) u16 As[128*32];
  __shared__ __attribute__((aligned(16))) u16 Bs[256*32];
  __shared__ float sS[128], sSS[128];
  A  += blockIdx.z * zA;
  Bw += blockIdx.z * zB;
  const int ccol0 = (int)blockIdx.z * zCcol;
  const int tid = threadIdx.x, lane = tid & 63, w = tid >> 6;
  const int mrow = lane & 15, quad = lane >> 4;
  const size_t mbase = (size_t)blockIdx.x*128;
  const int wr = (w&1)*64, wc = (w>>1)*64;
  if (tid < 128){ sS[tid] = 0.f; sSS[tid] = 0.f; }
  f32x4 acc[4][4];
  #pragma unroll
  for (int i=0;i<4;++i)
    #pragma unroll
    for (int j=0;j<4;++j)
      #pragma unroll
      for (int r=0;r<4;++r) acc[i][j][r] = 0.f;
  const int sr = tid >> 2, sk = (tid & 3)*8;
  u16* ldA  = &As[w*512];
  u16* ldB0 = &Bs[w*512];
  u16* ldB1 = &Bs[4096 + w*512];
  for (int k0 = 0; k0 < 256; k0 += 32){
    __syncthreads();
    async_copy16(A  + (mbase + sr)*(size_t)lda + k0 + sk, ldA);
    async_copy16(Bw + (size_t)sr*256        + k0 + sk, ldB0);
    async_copy16(Bw + (size_t)(128+sr)*256  + k0 + sk, ldB1);
    __syncthreads();
    bf16x8 af[4], bf[4];
    #pragma unroll
    for (int rt=0;rt<4;++rt) af[rt] = *(const bf16x8*)&As[(wr+rt*16+mrow)*32 + quad*8];
    #pragma unroll
    for (int ct=0;ct<4;++ct) bf[ct] = *(const bf16x8*)&Bs[(wc+ct*16+mrow)*32 + quad*8];
    #pragma unroll
    for (int rt=0;rt<4;++rt)
      #pragma unroll
      for (int ct=0;ct<4;++ct) acc[rt][ct] = MFMA16(af[rt], bf[ct], acc[rt][ct]);
  }
  #pragma unroll
  for (int rt=0;rt<4;++rt)
    #pragma unroll
    for (int r=0;r<4;++r){
      float s  = acc[rt][0][r]+acc[rt][1][r]+acc[rt][2][r]+acc[rt][3][r];
      float ss = acc[rt][0][r]*acc[rt][0][r]+acc[rt][1][r]*acc[rt][1][r]
               + acc[rt][2][r]*acc[rt][2][r]+acc[rt][3][r]*acc[rt][3][r];
      s  = rowsum16(s);
      ss = rowsum16(ss);
      if (mrow == 0){
        const int row = wr + rt*16 + quad*4 + r;
        atomicAdd(&sS[row],  s);
        atomicAdd(&sSS[row], ss);
      }
    }
  __syncthreads();
  #pragma unroll
  for (int ct=0;ct<4;++ct){
    const int col = wc + ct*16 + mrow;
    const float gv = g[col], bv = bta[col];
    #pragma unroll
    for (int rt=0;rt<4;++rt)
      #pragma unroll
      for (int r=0;r<4;++r){
        const int row = wr + rt*16 + quad*4 + r;
        const float mu = sS[row]*(1.f/256.f);
        const float var = sSS[row]*(1.f/256.f) - mu*mu;
        const float rs = rsqrtf(var + 1e-5f);
        C[(mbase+row)*(size_t)ldc + ccol0 + col] = f2b((acc[rt][ct][r]-mu)*rs*gv + bv);
      }
  }
}

// ---------------- fused per-neighbor attention kernel (v13: merged loop + LDS v-gather) ----------------
#define DP   264
#define RELP 40
__global__ __launch_bounds__(512,4) void attn_k(
    const float* __restrict__ xyz, const int* __restrict__ idxb,
    const u16* __restrict__ lnqkv, const u16* __restrict__ qa, const u16* __restrict__ ka,
    const u16* __restrict__ mcomb, const u16* __restrict__ wp2, const u16* __restrict__ wa2,
    const u16* __restrict__ wp1pk, u16* __restrict__ res){
  __shared__ __attribute__((aligned(16))) u16 h1buf[64*DP];   // h1, later v rows
  __shared__ __attribute__((aligned(16))) u16 h2buf[64*DP];
  __shared__ __attribute__((aligned(16))) u16 srel[64*RELP];
  __shared__ int sidx[64];
  const int tid = threadIdx.x;
  const int b = blockIdx.x >> 10;
  const int nbase = (blockIdx.x & 1023) << 2;
  const size_t gb = (size_t)b << 12;
  if (tid < 64){
    const int m = tid;
    const int im = idxb[(gb + nbase + (m>>4))*16 + (m&15)] & 4095;
    sidx[m] = im;
    const int nn = nbase + (m>>4);
    const float* pq = xyz + (gb+nn)*3;
    const float* pm = xyz + (gb+im)*3;
    const float rx = pq[0]-pm[0], ry = pq[1]-pm[1], rz = pq[2]-pm[2];
    uint4 a; a.x = pk2f(rx,ry); a.y = pk2f(rz,0.f); a.z = 0u; a.w = 0u;
    uint4 z; z.x = z.y = z.z = z.w = 0u;
    *(uint4*)&srel[m*RELP]    = a;
    *(uint4*)&srel[m*RELP+8]  = z;
    *(uint4*)&srel[m*RELP+16] = z;
    *(uint4*)&srel[m*RELP+24] = z;
  }
  __syncthreads();
  const int lane = tid & 63, w = tid >> 6;
  const int mrow = lane & 15, quad = lane >> 4;
  const int fr = w << 5;
  {
    bf16x8 aW[2], bR[4];
    #pragma unroll
    for (int ht=0;ht<2;++ht) aW[ht] = *(const bf16x8*)&wp1pk[(fr+ht*16+mrow)*32 + quad*8];
    #pragma unroll
    for (int mt=0;mt<4;++mt) bR[mt] = *(const bf16x8*)&srel[(mt*16+mrow)*RELP + quad*8];
    #pragma unroll
    for (int ht=0;ht<2;++ht)
      #pragma unroll
      for (int mt=0;mt<4;++mt){
        f32x4 hz;
        #pragma unroll
        for (int r=0;r<4;++r) hz[r]=0.f;
        hz = MFMA16(aW[ht], bR[mt], hz);
        float h0 = hz[0]>0.f?hz[0]:0.f, h1v = hz[1]>0.f?hz[1]:0.f;
        float h2v = hz[2]>0.f?hz[2]:0.f, h3 = hz[3]>0.f?hz[3]:0.f;
        uint2 o; o.x = pk2f(h0,h1v); o.y = pk2f(h2v,h3);
        *(uint2*)&h1buf[(mt*16+mrow)*DP + fr + ht*16 + quad*4] = o;
      }
  }
  int midx[4];
  #pragma unroll
  for (int mt = 0; mt < 4; ++mt) midx[mt] = sidx[mt*16 + mrow];
  __syncthreads();
  f32x4 at[2][4], av[2][4];
  #pragma unroll
  for (int i=0;i<2;++i)
    #pragma unroll
    for (int j=0;j<4;++j)
      #pragma unroll
      for (int r=0;r<4;++r){ at[i][j][r]=0.f; av[i][j][r]=0.f; }
  #pragma unroll 1
  for (int ks = 0; ks < 8; ++ks){
    const int koff = ks*32 + quad*8;
    bf16x8 aM[2], aP[2], bH[4];
    #pragma unroll
    for (int ft=0;ft<2;++ft){
      aM[ft] = *(const bf16x8*)&mcomb[(fr+ft*16+mrow)*256 + koff];
      aP[ft] = *(const bf16x8*)&wp2  [(fr+ft*16+mrow)*256 + koff];
    }
    #pragma unroll
    for (int mt=0;mt<4;++mt) bH[mt] = *(const bf16x8*)&h1buf[(mt*16+mrow)*DP + koff];
    #pragma unroll
    for (int ft=0;ft<2;++ft)
      #pragma unroll
      for (int mt=0;mt<4;++mt){
        at[ft][mt] = MFMA16(aM[ft], bH[mt], at[ft][mt]);
        av[ft][mt] = MFMA16(bH[mt], aP[ft], av[ft][mt]);
      }
  }
  uint2 qkp[2][4];
  #pragma unroll
  for (int ft = 0; ft < 2; ++ft)
    #pragma unroll
    for (int mt = 0; mt < 4; ++mt){
      const int f = fr + ft*16 + quad*4;
      const uint2 uq = *(const uint2*)&qa[(gb + nbase + mt)*256 + f];
      const uint2 uk = *(const uint2*)&ka[(gb + (size_t)midx[mt])*256 + f];
      uint2 o;
      o.x = pk2f(b2f(uq.x&0xffff)-b2f(uk.x&0xffff), b2f(uq.x>>16)-b2f(uk.x>>16));
      o.y = pk2f(b2f(uq.y&0xffff)-b2f(uk.y&0xffff), b2f(uq.y>>16)-b2f(uk.y>>16));
      qkp[ft][mt] = o;
    }
  #pragma unroll
  for (int ft=0;ft<2;++ft)
    #pragma unroll
    for (int mt=0;mt<4;++mt){
      const int moff = (mt*16+mrow)*DP + fr + ft*16 + quad*4;
      const uint2 qv = qkp[ft][mt];
      float t0 = at[ft][mt][0] + b2f(qv.x&0xffff);
      float t1 = at[ft][mt][1] + b2f(qv.x>>16);
      float t2 = at[ft][mt][2] + b2f(qv.y&0xffff);
      float t3 = at[ft][mt][3] + b2f(qv.y>>16);
      t0 = t0>0.f?t0:0.f; t1 = t1>0.f?t1:0.f; t2 = t2>0.f?t2:0.f; t3 = t3>0.f?t3:0.f;
      uint2 o; o.x = pk2f(t0,t1); o.y = pk2f(t2,t3);
      *(uint2*)&h2buf[moff] = o;
    }
  __syncthreads();
  {
    const int vrow = tid >> 3, c8 = tid & 7;
    const u16* src = lnqkv + (gb + (size_t)sidx[vrow])*768 + 512;
    u16* dst = &h1buf[vrow*DP];
    #pragma unroll
    for (int i = 0; i < 4; ++i){
      const int e = (c8 + 8*i)*8;
      *(uint4*)&dst[e] = *(const uint4*)&src[e];
    }
  }
  f32x4 al[2][4];
  #pragma unroll
  for (int i=0;i<2;++i)
    #pragma unroll
    for (int j=0;j<4;++j)
      #pragma unroll
      for (int r=0;r<4;++r) al[i][j][r]=0.f;
  #pragma unroll 2
  for (int ks = 0; ks < 8; ++ks){
    const int koff = ks*32 + quad*8;
    bf16x8 aW[2], bH[4];
    #pragma unroll
    for (int gt=0;gt<2;++gt) aW[gt] = *(const bf16x8*)&wa2[(fr+gt*16+mrow)*256 + koff];
    #pragma unroll
    for (int mt=0;mt<4;++mt) bH[mt] = *(const bf16x8*)&h2buf[(mt*16+mrow)*DP + koff];
    #pragma unroll
    for (int gt=0;gt<2;++gt)
      #pragma unroll
      for (int mt=0;mt<4;++mt) al[gt][mt] = MFMA16(bH[mt], aW[gt], al[gt][mt]);
  }
  __syncthreads();
  const float sc = 0.0901684f;   // log2(e)/sqrt(256)
  #pragma unroll
  for (int gt=0;gt<2;++gt)
    #pragma unroll
    for (int mt=0;mt<4;++mt){
      float prs = 0.f, wgs = 0.f;
      #pragma unroll
      for (int r=0;r<4;++r){
        const int vr = mt*16 + quad*4 + r;
        const float val = av[gt][mt][r] + b2f((u32)h1buf[vr*DP + fr + gt*16 + mrow]);
        const float pr = exp2f(al[gt][mt][r]*sc);
        prs += pr;
        wgs += pr*val;
      }
      prs += __shfl_xor(prs, 16, 64); prs += __shfl_xor(prs, 32, 64);
      wgs += __shfl_xor(wgs, 16, 64); wgs += __shfl_xor(wgs, 32, 64);
      const float rv = wgs * __builtin_amdgcn_rcpf(prs);
      if (quad == 0)
        res[(gb + nbase + mt)*256 + fr + gt*16 + mrow] = f2b(rv);
    }
}

// ---------------- final: out = ln(r1 @ W_post.T + b_post)*g+b + features ----------------
__global__ __launch_bounds__(256,2) void d2_k(
    const u16* __restrict__ r1, const u16* __restrict__ wpost,
    const float* __restrict__ bpost, const float* __restrict__ g, const float* __restrict__ bt,
    const float* __restrict__ feat, float* __restrict__ out){
  const int tid = threadIdx.x, lane = tid & 63, w = tid >> 6;
  const int mrow = lane & 15, quad = lane >> 4;
  const size_t rb = (size_t)blockIdx.x*128 + w*32;
  f32x4 acc[2][4];
  #pragma unroll
  for (int i=0;i<2;++i)
    #pragma unroll
    for (int j=0;j<4;++j)
      #pragma unroll
      for (int r=0;r<4;++r) acc[i][j][r]=0.f;
  #pragma unroll 1
  for (int ks = 0; ks < 8; ++ks){
    const int koff = ks*32 + quad*8;
    bf16x8 af[2], bf[4];
    #pragma unroll
    for (int rt=0;rt<2;++rt) af[rt] = *(const bf16x8*)&r1[(rb+rt*16+mrow)*256 + koff];
    #pragma unroll
    for (int ct=0;ct<4;++ct) bf[ct] = *(const bf16x8*)&wpost[(ct*16+mrow)*256 + koff];
    #pragma unroll
    for (int rt=0;rt<2;++rt)
      #pragma unroll
      for (int ct=0;ct<4;++ct) acc[rt][ct] = MFMA16(af[rt], bf[ct], acc[rt][ct]);
  }
  #pragma unroll
  for (int ct=0;ct<4;++ct){
    const float bv = bpost[ct*16+mrow];
    #pragma unroll
    for (int rt=0;rt<2;++rt)
      #pragma unroll
      for (int r=0;r<4;++r) acc[rt][ct][r] += bv;
  }
  #pragma unroll
  for (int rt=0;rt<2;++rt)
    #pragma unroll
    for (int r=0;r<4;++r){
      float s  = acc[rt][0][r]+acc[rt][1][r]+acc[rt][2][r]+acc[rt][3][r];
      float ss = acc[rt][0][r]*acc[rt][0][r]+acc[rt][1][r]*acc[rt][1][r]
               + acc[rt][2][r]*acc[rt][2][r]+acc[rt][3][r]*acc[rt][3][r];
      s  = rowsum16(s);
      ss = rowsum16(ss);
      const float mu = s*(1.f/64.f);
      const float var = ss*(1.f/64.f) - mu*mu;
      const float rs = rsqrtf(var + 1e-5f);
      const size_t row = rb + rt*16 + quad*4 + r;
      #pragma unroll
      for (int ct=0;ct<4;++ct){
        const int n = ct*16 + mrow;
        out[row*64 + n] = (acc[rt][ct][r]-mu)*rs*g[n] + bt[n] + feat[row*64 + n];
      }
    }
}

// ---------------- launcher ----------------
extern "C" void kernel_launch(void* const* d_in, const int* in_sizes, int n_in,
                              void* d_out, int out_size, void* d_ws, size_t ws_size,
                              hipStream_t stream){
  const float* xyz    = (const float*)d_in[0];
  const float* feat   = (const float*)d_in[1];
  const float* W_pre  = (const float*)d_in[2];
  const float* b_pre  = (const float*)d_in[3];
  const float* W_post = (const float*)d_in[4];
  const float* b_post = (const float*)d_in[5];
  const float* Wp1    = (const float*)d_in[6];
  const float* Wp2    = (const float*)d_in[7];
  const float* Wa1    = (const float*)d_in[8];
  const float* Wa2    = (const float*)d_in[9];
  const float* WQ     = (const float*)d_in[10];
  const float* WK     = (const float*)d_in[11];
  const float* WV     = (const float*)d_in[12];
  const float* Wproj  = (const float*)d_in[13];
  const float* g_dm   = (const float*)d_in[14];
  const float* b_dm   = (const float*)d_in[15];
  const float* g_dp   = (const float*)d_in[16];
  const float* b_dp   = (const float*)d_in[17];
  float* out = (float*)d_out;
  if (ws_size < WS_NEED) return;
  char* ws = (char*)d_ws;
  int* idxw   = (int*)(ws + OFF_IDX);
  u16* wqkvb  = (u16*)(ws + OFF_WQKV);
  u16* wa1b   = (u16*)(ws + OFF_WA1);
  u16* wa2b   = (u16*)(ws + OFF_WA2);
  u16* wp2b   = (u16*)(ws + OFF_WP2);
  u16* wprojb = (u16*)(ws + OFF_WPROJ);
  u16* wpostb = (u16*)(ws + OFF_WPOST);
  u16* mcombb = (u16*)(ws + OFF_MCOMB);
  u16* inp    = (u16*)(ws + OFF_INP);
  u16* lnqkv  = (u16*)(ws + OFF_LNQKV);
  u16* qab    = (u16*)(ws + OFF_QA);
  u16* kab    = (u16*)(ws + OFF_KA);
  u16* resb   = (u16*)(ws + OFF_RES);
  u16* r1b    = (u16*)(ws + OFF_R1);
  u16* wp1pk  = (u16*)(ws + OFF_WP1PK);

  // fused prologue: weight converts + wp1 pack + mcomb + kNN + inp GEMM (all independent)
  prep_k<<<3393,256,0,stream>>>(xyz, feat, W_pre, b_pre, WQ, WK, WV, Wa1, Wa2, Wp2,
                                Wproj, W_post, Wp1,
                                wqkvb, wa1b, wa2b, wp2b, wprojb, wpostb,
                                wp1pk, mcombb, idxw, inp);
  // lnqkv[:, z*256 : z*256+256] = ln(inp @ W{Q,K,V}.T)
  gemmln_k<<<dim3(128,1,3),512,0,stream>>>(inp,256,0, wqkvb,65536, lnqkv,768,256, g_dm,b_dm);
  // qa = ln(q) @ Wa1.T ; ka = ln(k) @ Wa1.T
  gemm128_k<<<dim3(128,2,2),256,0,stream>>>(lnqkv,768, wa1b,256, qab,256, 256, nullptr,
                                            256, 4194304);
  attn_k<<<4096,512,0,stream>>>(xyz,idxw,lnqkv,qab,kab,mcombb,wp2b,wa2b,wp1pk,resb);
  // r1 = ln(res @ Wproj.T)
  gemmln_k<<<dim3(128,1,1),512,0,stream>>>(resb,256,0, wprojb,0, r1b,256,0, g_dm,b_dm);
  d2_k<<<128,256,0,stream>>>(r1b,wpostb,b_post,g_dp,b_dp,feat,out);
}

// Round 16
// 497.693 us; speedup vs baseline: 1.0855x; 1.0546x over previous
//
#include <hip/hip_runtime.h>
#include <hip/hip_bf16.h>

typedef unsigned short u16;
typedef unsigned int   u32;
typedef __attribute__((ext_vector_type(8))) short bf16x8;
typedef __attribute__((ext_vector_type(4))) float f32x4;

#define MFMA16(a,b,c) __builtin_amdgcn_mfma_f32_16x16x32_bf16((a),(b),(c),0,0,0)

__device__ __forceinline__ float b2f(u32 h){ return __uint_as_float(h<<16); }
__device__ __forceinline__ u16 f2b(float f){
  u32 u = __float_as_uint(f);
  return (u16)((u + 0x7FFFu + ((u>>16)&1u))>>16);
}
// HW packed convert: v_cvt_pk_bf16_f32 (RNE)
__device__ __forceinline__ u32 pk2f(float a,float b){
  __hip_bfloat162 h = __float22bfloat162_rn(float2{a,b});
  return *reinterpret_cast<u32*>(&h);
}
__device__ __forceinline__ u32 umin32(u32 a,u32 b){ return a<b?a:b; }
__device__ __forceinline__ u32 umax32(u32 a,u32 b){ return a>b?a:b; }

// 16-lane row-sum on the VALU pipe via DPP row_ror
template<int CTRL>
__device__ __forceinline__ float dpp_add(float x){
  int t = __builtin_amdgcn_update_dpp(0, __float_as_int(x), CTRL, 0xF, 0xF, true);
  return x + __int_as_float(t);
}
__device__ __forceinline__ float rowsum16(float x){
  x = dpp_add<0x121>(x);
  x = dpp_add<0x122>(x);
  x = dpp_add<0x124>(x);
  x = dpp_add<0x128>(x);
  return x;
}

__device__ __forceinline__ void async_copy16(const void* g, void* l){
  __builtin_amdgcn_global_load_lds((const __attribute__((address_space(1))) u32*)g,
                                   (__attribute__((address_space(3))) u32*)l, 16, 0, 0);
}

// ---------------- workspace layout (bytes) ----------------
#define OFF_IDX    0ull
#define OFF_WQKV   3178496ull
#define OFF_WA1    3571712ull
#define OFF_WA2    3702784ull
#define OFF_WP2    3833856ull
#define OFF_WPROJ  3964928ull
#define OFF_WPOST  4096000ull
#define OFF_MCOMB  4128768ull
#define OFF_INP    4259840ull
#define OFF_LNQKV  37814272ull
#define OFF_QA     62980096ull
#define OFF_KA     71368704ull
#define OFF_RES    79757312ull
#define OFF_D1     88145920ull
#define WS_NEED    104923136ull
#define OFF_WP1PK  OFF_D1

// ---------------- fused prologue: weight converts + wp1 pack + mcomb + kNN + inp GEMM ----------------
__device__ __forceinline__ void ins16(u32 (&a)[16], u32 key){
  #pragma unroll
  for (int j = 15; j >= 1; --j) a[j] = umin32(umax32(a[j-1],key), a[j]);
  a[0] = umin32(a[0], key);
}

__device__ __forceinline__ float dist2(float ax,float ay,float az,float bx,float by,float bz){
  const float dx = ax-bx, dy = ay-by, dz = az-bz;
  return __fmaf_rn(dx,dx, __fmaf_rn(dy,dy, dz*dz));
}

__global__ __launch_bounds__(256,2) void prep_k(
    const float* __restrict__ xyz, const float* __restrict__ feat,
    const float* __restrict__ wpre, const float* __restrict__ bpre,
    const float* __restrict__ wq, const float* __restrict__ wk, const float* __restrict__ wv,
    const float* __restrict__ wa1, const float* __restrict__ wa2, const float* __restrict__ wp2,
    const float* __restrict__ wproj, const float* __restrict__ wpost,
    const float* __restrict__ wp1,
    u16* __restrict__ dwqkv, u16* __restrict__ dwa1, u16* __restrict__ dwa2,
    u16* __restrict__ dwp2, u16* __restrict__ dwproj, u16* __restrict__ dwpost,
    u16* __restrict__ dwp1pk, u16* __restrict__ dmcomb,
    int* __restrict__ idxout, u16* __restrict__ dinp){
  __shared__ __attribute__((aligned(16))) char smem[50464];
  const int bid = blockIdx.x, tid = threadIdx.x;
  if (bid < 1856){
    int id = bid*256 + tid;
    const float* s; u16* d; int off;
    if      (id <  65536){ s=wq;    d=dwqkv;        off=id; }
    else if (id < 131072){ s=wk;    d=dwqkv+65536;  off=id-65536; }
    else if (id < 196608){ s=wv;    d=dwqkv+131072; off=id-131072; }
    else if (id < 262144){ s=wa1;   d=dwa1;         off=id-196608; }
    else if (id < 327680){ s=wa2;   d=dwa2;         off=id-262144; }
    else if (id < 393216){ s=wp2;   d=dwp2;         off=id-327680; }
    else if (id < 458752){ s=wproj; d=dwproj;       off=id-393216; }
    else                 { s=wpost; d=dwpost;       off=id-458752; }
    d[off] = f2b(s[off]);
  } else if (bid == 1856){
    const int h = tid;
    const float w0 = wp1[h*3], w1 = wp1[h*3+1], w2 = wp1[h*3+2];
    uint4 a; a.x = pk2f(w0,w1); a.y = pk2f(w2,0.f); a.z = 0u; a.w = 0u;
    uint4 z; z.x = z.y = z.z = z.w = 0u;
    *(uint4*)&dwp1pk[h*32]    = a;
    *(uint4*)&dwp1pk[h*32+8]  = z;
    *(uint4*)&dwp1pk[h*32+16] = z;
    *(uint4*)&dwp1pk[h*32+24] = z;
  } else if (bid < 2113){
    const int f = bid - 1857, h = tid;
    float acc = 0.f;
    #pragma unroll 4
    for (int j = 0; j < 256; ++j) acc = __fmaf_rn(wa1[f*256+j], wp2[j*256+h], acc);
    dmcomb[f*256+h] = f2b(acc);
  } else if (bid < 3137){
    float* sx = (float*)smem; float* sy = sx + 4104; float* sz = sx + 8208;
    int* lcnt   = (int*)(smem + 49248);
    int* tcnt   = (int*)(smem + 49312);
    u32* tbuf   = (u32*)(smem + 49376);
    int* tiebuf = (int*)(smem + 49440);
    const int tb = bid - 2113;
    const int b  = tb >> 8;
    const int n0 = (tb & 255) << 4;
    const float* base = xyz + (size_t)b*12288;
    #pragma unroll
    for (int i = 0; i < 12; ++i){
      const float4 v = *(const float4*)(base + tid*48 + i*4);
      const float vv[4] = {v.x, v.y, v.z, v.w};
      #pragma unroll
      for (int j = 0; j < 4; ++j){
        const int e = i*4 + j;
        const int c = e % 3;
        const int m = tid*16 + e/3;
        float* arr = (c==0)?sx:((c==1)?sy:sz);
        arr[m + (m>>9)] = vv[j];
      }
    }
    if (tid < 16){ lcnt[tid] = 0; tcnt[tid] = 0; }
    __syncthreads();
    const int qi = tid >> 4, p = tid & 15;
    const int n = n0 + qi;
    const int sn = n + (n>>9);
    const float qx = sx[sn], qy = sy[sn], qz = sz[sn];
    u32 a[16];
    #pragma unroll
    for (int j = 0; j < 16; ++j) a[j] = 0xFFFFFFFFu;
    const int sb = p*256 + (p>>1);
    #pragma unroll 2
    for (int i = 0; i < 256; ++i){
      const float d2 = dist2(sx[sb+i],sy[sb+i],sz[sb+i],qx,qy,qz);
      ins16(a, __float_as_uint(d2));
    }
    #pragma unroll
    for (int s = 8; s >= 1; s >>= 1){
      u32 o[16];
      #pragma unroll
      for (int j = 0; j < 16; ++j) o[j] = __shfl_down(a[j], (unsigned)s, 64);
      if (p < s){
        #pragma unroll
        for (int j = 0; j < 16; ++j) ins16(a, o[j]);
      }
    }
    if (p == 0) tbuf[qi] = a[15];
    __syncthreads();
    const u32 T = tbuf[qi];
    int* orow = idxout + ((size_t)(b<<12)+n)*16;
    const int gbase = p*256;
    for (int i = 0; i < 256; ++i){
      const float d2 = dist2(sx[sb+i],sy[sb+i],sz[sb+i],qx,qy,qz);
      const u32 kb = __float_as_uint(d2);
      if (kb < T){
        const int pos = atomicAdd(&lcnt[qi],1);
        if (pos < 16) orow[pos] = gbase + i;
      } else if (kb == T){
        const int t = atomicAdd(&tcnt[qi],1);
        if (t < 16) tiebuf[qi*16+t] = gbase + i;
      }
    }
    __syncthreads();
    if (p == 0){
      int L = lcnt[qi]; if (L > 16) L = 16;
      int tc = tcnt[qi]; if (tc > 16) tc = 16;
      const int need = 16 - L;
      for (int r = 0; r < need; ++r){
        int best = 0x7FFFFFFF, bj = -1;
        for (int j = 0; j < tc; ++j){
          const int v = tiebuf[qi*16+j];
          if (v < best){ best = v; bj = j; }
        }
        if (bj >= 0){ tiebuf[qi*16+bj] = 0x7FFFFFFF; orow[L+r] = best; }
        else orow[L+r] = n;
      }
    }
  } else {
    // ---- inp = feat @ W_pre.T + b_pre (K=64), 128x128 tile
    u16* As = (u16*)smem;            // [128][72]
    u16* Bs = (u16*)smem + 9216;     // [128][72]
    const int tb = bid - 3137;
    const int mb = tb >> 1, nb = tb & 1;
    #pragma unroll
    for (int i = 0; i < 32; ++i){
      const int e = i*256 + tid;
      const int row = e >> 6, k = e & 63;
      As[row*72+k] = f2b(feat[(size_t)(mb*128)*64 + e]);
      Bs[row*72+k] = f2b(wpre[(size_t)(nb*128)*64 + e]);
    }
    __syncthreads();
    const int lane = tid & 63, w = tid >> 6;
    const int mrow = lane & 15, quad = lane >> 4;
    const int wr = (w&1)*64, wc = (w>>1)*64;
    f32x4 acc[4][4];
    #pragma unroll
    for (int i=0;i<4;++i)
      #pragma unroll
      for (int j=0;j<4;++j)
        #pragma unroll
        for (int r=0;r<4;++r) acc[i][j][r] = 0.f;
    #pragma unroll
    for (int ks = 0; ks < 2; ++ks){
      const int koff = ks*32 + quad*8;
      bf16x8 af[4], bf[4];
      #pragma unroll
      for (int rt=0;rt<4;++rt) af[rt] = *(const bf16x8*)&As[(wr+rt*16+mrow)*72 + koff];
      #pragma unroll
      for (int ct=0;ct<4;++ct) bf[ct] = *(const bf16x8*)&Bs[(wc+ct*16+mrow)*72 + koff];
      #pragma unroll
      for (int rt=0;rt<4;++rt)
        #pragma unroll
        for (int ct=0;ct<4;++ct) acc[rt][ct] = MFMA16(af[rt], bf[ct], acc[rt][ct]);
    }
    #pragma unroll
    for (int rt=0;rt<4;++rt)
      #pragma unroll
      for (int ct=0;ct<4;++ct){
        const size_t row0 = (size_t)mb*128 + wr + rt*16 + quad*4;
        const int col = nb*128 + wc + ct*16 + mrow;
        const float bv = bpre[col];
        #pragma unroll
        for (int r=0;r<4;++r) dinp[(row0+r)*256 + col] = f2b(acc[rt][ct][r] + bv);
      }
  }
}

// ---------------- fused GEMM+LN (+second GEMM for qa/ka): 64-row tiles ----------------
// z=0: qa = ln(inp@WQ.T) @ Wa1.T   z=1: ka = ln(inp@WK.T) @ Wa1.T
// z=2: lnv slice = ln(inp@WV.T)  (written to lnqkv[...,512:768])
// 512 threads = 8 waves. Phase1 wave: rows (w&1)*32..+32, cols (w>>1)*64..+64.
#define LNP 264
__global__ __launch_bounds__(512,2) void gemmlnqa_k(
    const u16* __restrict__ inp, const u16* __restrict__ wqkv, const u16* __restrict__ wa1,
    u16* __restrict__ qa, u16* __restrict__ ka, u16* __restrict__ lnqkv,
    const float* __restrict__ g, const float* __restrict__ bta){
  __shared__ __attribute__((aligned(16))) u16 As[64*32];      // 4 KB
  __shared__ __attribute__((aligned(16))) u16 Bs[256*32];     // 16 KB
  __shared__ __attribute__((aligned(16))) u16 lnbuf[64*LNP];  // 33.8 KB
  __shared__ float sS[64], sSS[64];
  const int z = blockIdx.z;
  const u16* wsel = wqkv + z*65536;
  const int tid = threadIdx.x, lane = tid & 63, w = tid >> 6;
  const int mrow = lane & 15, quad = lane >> 4;
  const size_t mbase = (size_t)blockIdx.x*64;
  const int wr = (w&1)*32, wc = (w>>1)*64;
  if (tid < 64){ sS[tid] = 0.f; sSS[tid] = 0.f; }
  f32x4 acc[2][4];
  #pragma unroll
  for (int i=0;i<2;++i)
    #pragma unroll
    for (int j=0;j<4;++j)
      #pragma unroll
      for (int r=0;r<4;++r) acc[i][j][r] = 0.f;
  const int sr = tid >> 2, sk = (tid & 3)*8;
  // ---- phase 1: X = inp(64 rows) @ wsel.T
  for (int k0 = 0; k0 < 256; k0 += 32){
    __syncthreads();
    if (tid < 256) async_copy16(inp + (mbase + sr)*256 + k0 + sk, &As[w*512]);
    async_copy16(wsel + (size_t)sr*256       + k0 + sk, &Bs[w*512]);
    async_copy16(wsel + (size_t)(128+sr)*256 + k0 + sk, &Bs[4096 + w*512]);
    __syncthreads();
    bf16x8 af[2], bf[4];
    #pragma unroll
    for (int rt=0;rt<2;++rt) af[rt] = *(const bf16x8*)&As[(wr+rt*16+mrow)*32 + quad*8];
    #pragma unroll
    for (int ct=0;ct<4;++ct) bf[ct] = *(const bf16x8*)&Bs[(wc+ct*16+mrow)*32 + quad*8];
    #pragma unroll
    for (int rt=0;rt<2;++rt)
      #pragma unroll
      for (int ct=0;ct<4;++ct) acc[rt][ct] = MFMA16(af[rt], bf[ct], acc[rt][ct]);
  }
  // row stats (f32) across 4 col-waves
  #pragma unroll
  for (int rt=0;rt<2;++rt)
    #pragma unroll
    for (int r=0;r<4;++r){
      float s  = acc[rt][0][r]+acc[rt][1][r]+acc[rt][2][r]+acc[rt][3][r];
      float ss = acc[rt][0][r]*acc[rt][0][r]+acc[rt][1][r]*acc[rt][1][r]
               + acc[rt][2][r]*acc[rt][2][r]+acc[rt][3][r]*acc[rt][3][r];
      s  = rowsum16(s);
      ss = rowsum16(ss);
      if (mrow == 0){
        const int row = wr + rt*16 + quad*4 + r;
        atomicAdd(&sS[row],  s);
        atomicAdd(&sSS[row], ss);
      }
    }
  __syncthreads();
  // apply LN
  #pragma unroll
  for (int ct=0;ct<4;++ct){
    const int col = wc + ct*16 + mrow;
    const float gv = g[col], bv = bta[col];
    #pragma unroll
    for (int rt=0;rt<2;++rt)
      #pragma unroll
      for (int r=0;r<4;++r){
        const int row = wr + rt*16 + quad*4 + r;
        const float mu = sS[row]*(1.f/256.f);
        const float var = sSS[row]*(1.f/256.f) - mu*mu;
        const float rs = rsqrtf(var + 1e-5f);
        const u16 hv = f2b((acc[rt][ct][r]-mu)*rs*gv + bv);
        if (z == 2) lnqkv[(mbase+row)*768 + 512 + col] = hv;
        else        lnbuf[row*LNP + col] = hv;
      }
  }
  if (z == 2) return;
  // ---- phase 2: out = lnbuf @ Wa1.T  (Bs restaged per k-step)
  u16* outp = (z == 0) ? qa : ka;
  f32x4 ac2[2][4];
  #pragma unroll
  for (int i=0;i<2;++i)
    #pragma unroll
    for (int j=0;j<4;++j)
      #pragma unroll
      for (int r=0;r<4;++r) ac2[i][j][r] = 0.f;
  for (int k0 = 0; k0 < 256; k0 += 32){
    __syncthreads();
    async_copy16(wa1 + (size_t)sr*256       + k0 + sk, &Bs[w*512]);
    async_copy16(wa1 + (size_t)(128+sr)*256 + k0 + sk, &Bs[4096 + w*512]);
    __syncthreads();
    bf16x8 af[2], bf[4];
    #pragma unroll
    for (int rt=0;rt<2;++rt) af[rt] = *(const bf16x8*)&lnbuf[(wr+rt*16+mrow)*LNP + k0 + quad*8];
    #pragma unroll
    for (int ct=0;ct<4;++ct) bf[ct] = *(const bf16x8*)&Bs[(wc+ct*16+mrow)*32 + quad*8];
    #pragma unroll
    for (int rt=0;rt<2;++rt)
      #pragma unroll
      for (int ct=0;ct<4;++ct) ac2[rt][ct] = MFMA16(af[rt], bf[ct], ac2[rt][ct]);
  }
  #pragma unroll
  for (int rt=0;rt<2;++rt)
    #pragma unroll
    for (int ct=0;ct<4;++ct){
      const size_t row0 = mbase + wr + rt*16 + quad*4;
      const int col = wc + ct*16 + mrow;
      #pragma unroll
      for (int r=0;r<4;++r) outp[(row0+r)*256 + col] = f2b(ac2[rt][ct][r]);
    }
}

// ---------------- fused: out = ln( ln(res@Wproj.T) @ Wpost.T + bpost )*g+b + feat ----------------
// 64-row tiles, 512 threads. Phase1 like gemmlnqa. Phase2: 64 cols; wave = 16 rows x 32 cols.
__global__ __launch_bounds__(512,2) void projpost_k(
    const u16* __restrict__ res, const u16* __restrict__ wproj, const u16* __restrict__ wpost,
    const float* __restrict__ bpost,
    const float* __restrict__ g_dm, const float* __restrict__ b_dm,
    const float* __restrict__ g_dp, const float* __restrict__ b_dp,
    const float* __restrict__ feat, float* __restrict__ out){
  __shared__ __attribute__((aligned(16))) u16 As[64*32];
  __shared__ __attribute__((aligned(16))) u16 Bs[256*32];
  __shared__ __attribute__((aligned(16))) u16 lnbuf[64*LNP];
  __shared__ float sS[64], sSS[64], sS2[64], sSS2[64];
  const int tid = threadIdx.x, lane = tid & 63, w = tid >> 6;
  const int mrow = lane & 15, quad = lane >> 4;
  const size_t mbase = (size_t)blockIdx.x*64;
  const int wr = (w&1)*32, wc = (w>>1)*64;
  if (tid < 64){ sS[tid]=0.f; sSS[tid]=0.f; sS2[tid]=0.f; sSS2[tid]=0.f; }
  f32x4 acc[2][4];
  #pragma unroll
  for (int i=0;i<2;++i)
    #pragma unroll
    for (int j=0;j<4;++j)
      #pragma unroll
      for (int r=0;r<4;++r) acc[i][j][r] = 0.f;
  const int sr = tid >> 2, sk = (tid & 3)*8;
  for (int k0 = 0; k0 < 256; k0 += 32){
    __syncthreads();
    if (tid < 256) async_copy16(res + (mbase + sr)*256 + k0 + sk, &As[w*512]);
    async_copy16(wproj + (size_t)sr*256       + k0 + sk, &Bs[w*512]);
    async_copy16(wproj + (size_t)(128+sr)*256 + k0 + sk, &Bs[4096 + w*512]);
    __syncthreads();
    bf16x8 af[2], bf[4];
    #pragma unroll
    for (int rt=0;rt<2;++rt) af[rt] = *(const bf16x8*)&As[(wr+rt*16+mrow)*32 + quad*8];
    #pragma unroll
    for (int ct=0;ct<4;++ct) bf[ct] = *(const bf16x8*)&Bs[(wc+ct*16+mrow)*32 + quad*8];
    #pragma unroll
    for (int rt=0;rt<2;++rt)
      #pragma unroll
      for (int ct=0;ct<4;++ct) acc[rt][ct] = MFMA16(af[rt], bf[ct], acc[rt][ct]);
  }
  #pragma unroll
  for (int rt=0;rt<2;++rt)
    #pragma unroll
    for (int r=0;r<4;++r){
      float s  = acc[rt][0][r]+acc[rt][1][r]+acc[rt][2][r]+acc[rt][3][r];
      float ss = acc[rt][0][r]*acc[rt][0][r]+acc[rt][1][r]*acc[rt][1][r]
               + acc[rt][2][r]*acc[rt][2][r]+acc[rt][3][r]*acc[rt][3][r];
      s  = rowsum16(s);
      ss = rowsum16(ss);
      if (mrow == 0){
        const int row = wr + rt*16 + quad*4 + r;
        atomicAdd(&sS[row],  s);
        atomicAdd(&sSS[row], ss);
      }
    }
  __syncthreads();
  #pragma unroll
  for (int ct=0;ct<4;++ct){
    const int col = wc + ct*16 + mrow;
    const float gv = g_dm[col], bv = b_dm[col];
    #pragma unroll
    for (int rt=0;rt<2;++rt)
      #pragma unroll
      for (int r=0;r<4;++r){
        const int row = wr + rt*16 + quad*4 + r;
        const float mu = sS[row]*(1.f/256.f);
        const float var = sSS[row]*(1.f/256.f) - mu*mu;
        const float rs = rsqrtf(var + 1e-5f);
        lnbuf[row*LNP + col] = f2b((acc[rt][ct][r]-mu)*rs*gv + bv);
      }
  }
  // ---- phase 2: d = lnbuf @ Wpost.T + bpost  (64 cols); wave = 16 rows x 32 cols
  const int wr2 = (w & 3)*16, wc2 = (w >> 2)*32;
  f32x4 ac2[2];
  #pragma unroll
  for (int j=0;j<2;++j)
    #pragma unroll
    for (int r=0;r<4;++r) ac2[j][r] = 0.f;
  for (int k0 = 0; k0 < 256; k0 += 32){
    __syncthreads();
    if (tid < 256) async_copy16(wpost + (size_t)sr*256 + k0 + sk, &Bs[w*512]);
    __syncthreads();
    bf16x8 af, bf[2];
    af = *(const bf16x8*)&lnbuf[(wr2+mrow)*LNP + k0 + quad*8];
    #pragma unroll
    for (int ct=0;ct<2;++ct) bf[ct] = *(const bf16x8*)&Bs[(wc2+ct*16+mrow)*32 + quad*8];
    #pragma unroll
    for (int ct=0;ct<2;++ct) ac2[ct] = MFMA16(af, bf[ct], ac2[ct]);
  }
  #pragma unroll
  for (int ct=0;ct<2;++ct){
    const float bv = bpost[wc2 + ct*16 + mrow];
    #pragma unroll
    for (int r=0;r<4;++r) ac2[ct][r] += bv;
  }
  #pragma unroll
  for (int r=0;r<4;++r){
    float s  = ac2[0][r] + ac2[1][r];
    float ss = ac2[0][r]*ac2[0][r] + ac2[1][r]*ac2[1][r];
    s  = rowsum16(s);
    ss = rowsum16(ss);
    if (mrow == 0){
      const int row = wr2 + quad*4 + r;
      atomicAdd(&sS2[row],  s);
      atomicAdd(&sSS2[row], ss);
    }
  }
  __syncthreads();
  #pragma unroll
  for (int ct=0;ct<2;++ct){
    const int col = wc2 + ct*16 + mrow;
    const float gv = g_dp[col], bv = b_dp[col];
    #pragma unroll
    for (int r=0;r<4;++r){
      const int row = wr2 + quad*4 + r;
      const float mu = sS2[row]*(1.f/64.f);
      const float var = sSS2[row]*(1.f/64.f) - mu*mu;
      const float rs = rsqrtf(var + 1e-5f);
      const size_t grow = mbase + row;
      out[grow*64 + col] = (ac2[ct][r]-mu)*rs*gv + bv + feat[grow*64 + col];
    }
  }
}

// ---------------- fused per-neighbor attention kernel (v13: merged loop + LDS v-gather) ----------------
#define DP   264
#define RELP 40
__global__ __launch_bounds__(512,4) void attn_k(
    const float* __restrict__ xyz, const int* __restrict__ idxb,
    const u16* __restrict__ lnqkv, const u16* __restrict__ qa, const u16* __restrict__ ka,
    const u16* __restrict__ mcomb, const u16* __restrict__ wp2, const u16* __restrict__ wa2,
    const u16* __restrict__ wp1pk, u16* __restrict__ res){
  __shared__ __attribute__((aligned(16))) u16 h1buf[64*DP];   // h1, later v rows
  __shared__ __attribute__((aligned(16))) u16 h2buf[64*DP];
  __shared__ __attribute__((aligned(16))) u16 srel[64*RELP];
  __shared__ int sidx[64];
  const int tid = threadIdx.x;
  const int b = blockIdx.x >> 10;
  const int nbase = (blockIdx.x & 1023) << 2;
  const size_t gb = (size_t)b << 12;
  if (tid < 64){
    const int m = tid;
    const int im = idxb[(gb + nbase + (m>>4))*16 + (m&15)] & 4095;
    sidx[m] = im;
    const int nn = nbase + (m>>4);
    const float* pq = xyz + (gb+nn)*3;
    const float* pm = xyz + (gb+im)*3;
    const float rx = pq[0]-pm[0], ry = pq[1]-pm[1], rz = pq[2]-pm[2];
    uint4 a; a.x = pk2f(rx,ry); a.y = pk2f(rz,0.f); a.z = 0u; a.w = 0u;
    uint4 z; z.x = z.y = z.z = z.w = 0u;
    *(uint4*)&srel[m*RELP]    = a;
    *(uint4*)&srel[m*RELP+8]  = z;
    *(uint4*)&srel[m*RELP+16] = z;
    *(uint4*)&srel[m*RELP+24] = z;
  }
  __syncthreads();
  const int lane = tid & 63, w = tid >> 6;
  const int mrow = lane & 15, quad = lane >> 4;
  const int fr = w << 5;
  {
    bf16x8 aW[2], bR[4];
    #pragma unroll
    for (int ht=0;ht<2;++ht) aW[ht] = *(const bf16x8*)&wp1pk[(fr+ht*16+mrow)*32 + quad*8];
    #pragma unroll
    for (int mt=0;mt<4;++mt) bR[mt] = *(const bf16x8*)&srel[(mt*16+mrow)*RELP + quad*8];
    #pragma unroll
    for (int ht=0;ht<2;++ht)
      #pragma unroll
      for (int mt=0;mt<4;++mt){
        f32x4 hz;
        #pragma unroll
        for (int r=0;r<4;++r) hz[r]=0.f;
        hz = MFMA16(aW[ht], bR[mt], hz);
        float h0 = hz[0]>0.f?hz[0]:0.f, h1v = hz[1]>0.f?hz[1]:0.f;
        float h2v = hz[2]>0.f?hz[2]:0.f, h3 = hz[3]>0.f?hz[3]:0.f;
        uint2 o; o.x = pk2f(h0,h1v); o.y = pk2f(h2v,h3);
        *(uint2*)&h1buf[(mt*16+mrow)*DP + fr + ht*16 + quad*4] = o;
      }
  }
  int midx[4];
  #pragma unroll
  for (int mt = 0; mt < 4; ++mt) midx[mt] = sidx[mt*16 + mrow];
  __syncthreads();
  f32x4 at[2][4], av[2][4];
  #pragma unroll
  for (int i=0;i<2;++i)
    #pragma unroll
    for (int j=0;j<4;++j)
      #pragma unroll
      for (int r=0;r<4;++r){ at[i][j][r]=0.f; av[i][j][r]=0.f; }
  #pragma unroll 1
  for (int ks = 0; ks < 8; ++ks){
    const int koff = ks*32 + quad*8;
    bf16x8 aM[2], aP[2], bH[4];
    #pragma unroll
    for (int ft=0;ft<2;++ft){
      aM[ft] = *(const bf16x8*)&mcomb[(fr+ft*16+mrow)*256 + koff];
      aP[ft] = *(const bf16x8*)&wp2  [(fr+ft*16+mrow)*256 + koff];
    }
    #pragma unroll
    for (int mt=0;mt<4;++mt) bH[mt] = *(const bf16x8*)&h1buf[(mt*16+mrow)*DP + koff];
    #pragma unroll
    for (int ft=0;ft<2;++ft)
      #pragma unroll
      for (int mt=0;mt<4;++mt){
        at[ft][mt] = MFMA16(aM[ft], bH[mt], at[ft][mt]);
        av[ft][mt] = MFMA16(bH[mt], aP[ft], av[ft][mt]);
      }
  }
  uint2 qkp[2][4];
  #pragma unroll
  for (int ft = 0; ft < 2; ++ft)
    #pragma unroll
    for (int mt = 0; mt < 4; ++mt){
      const int f = fr + ft*16 + quad*4;
      const uint2 uq = *(const uint2*)&qa[(gb + nbase + mt)*256 + f];
      const uint2 uk = *(const uint2*)&ka[(gb + (size_t)midx[mt])*256 + f];
      uint2 o;
      o.x = pk2f(b2f(uq.x&0xffff)-b2f(uk.x&0xffff), b2f(uq.x>>16)-b2f(uk.x>>16));
      o.y = pk2f(b2f(uq.y&0xffff)-b2f(uk.y&0xffff), b2f(uq.y>>16)-b2f(uk.y>>16));
      qkp[ft][mt] = o;
    }
  #pragma unroll
  for (int ft=0;ft<2;++ft)
    #pragma unroll
    for (int mt=0;mt<4;++mt){
      const int moff = (mt*16+mrow)*DP + fr + ft*16 + quad*4;
      const uint2 qv = qkp[ft][mt];
      float t0 = at[ft][mt][0] + b2f(qv.x&0xffff);
      float t1 = at[ft][mt][1] + b2f(qv.x>>16);
      float t2 = at[ft][mt][2] + b2f(qv.y&0xffff);
      float t3 = at[ft][mt][3] + b2f(qv.y>>16);
      t0 = t0>0.f?t0:0.f; t1 = t1>0.f?t1:0.f; t2 = t2>0.f?t2:0.f; t3 = t3>0.f?t3:0.f;
      uint2 o; o.x = pk2f(t0,t1); o.y = pk2f(t2,t3);
      *(uint2*)&h2buf[moff] = o;
    }
  __syncthreads();
  {
    const int vrow = tid >> 3, c8 = tid & 7;
    const u16* src = lnqkv + (gb + (size_t)sidx[vrow])*768 + 512;
    u16* dst = &h1buf[vrow*DP];
    #pragma unroll
    for (int i = 0; i < 4; ++i){
      const int e = (c8 + 8*i)*8;
      *(uint4*)&dst[e] = *(const uint4*)&src[e];
    }
  }
  f32x4 al[2][4];
  #pragma unroll
  for (int i=0;i<2;++i)
    #pragma unroll
    for (int j=0;j<4;++j)
      #pragma unroll
      for (int r=0;r<4;++r) al[i][j][r]=0.f;
  #pragma unroll 2
  for (int ks = 0; ks < 8; ++ks){
    const int koff = ks*32 + quad*8;
    bf16x8 aW[2], bH[4];
    #pragma unroll
    for (int gt=0;gt<2;++gt) aW[gt] = *(const bf16x8*)&wa2[(fr+gt*16+mrow)*256 + koff];
    #pragma unroll
    for (int mt=0;mt<4;++mt) bH[mt] = *(const bf16x8*)&h2buf[(mt*16+mrow)*DP + koff];
    #pragma unroll
    for (int gt=0;gt<2;++gt)
      #pragma unroll
      for (int mt=0;mt<4;++mt) al[gt][mt] = MFMA16(bH[mt], aW[gt], al[gt][mt]);
  }
  __syncthreads();
  const float sc = 0.0901684f;   // log2(e)/sqrt(256)
  #pragma unroll
  for (int gt=0;gt<2;++gt)
    #pragma unroll
    for (int mt=0;mt<4;++mt){
      float prs = 0.f, wgs = 0.f;
      #pragma unroll
      for (int r=0;r<4;++r){
        const int vr = mt*16 + quad*4 + r;
        const float val = av[gt][mt][r] + b2f((u32)h1buf[vr*DP + fr + gt*16 + mrow]);
        const float pr = exp2f(al[gt][mt][r]*sc);
        prs += pr;
        wgs += pr*val;
      }
      prs += __shfl_xor(prs, 16, 64); prs += __shfl_xor(prs, 32, 64);
      wgs += __shfl_xor(wgs, 16, 64); wgs += __shfl_xor(wgs, 32, 64);
      const float rv = wgs * __builtin_amdgcn_rcpf(prs);
      if (quad == 0)
        res[(gb + nbase + mt)*256 + fr + gt*16 + mrow] = f2b(rv);
    }
}

// ---------------- launcher ----------------
extern "C" void kernel_launch(void* const* d_in, const int* in_sizes, int n_in,
                              void* d_out, int out_size, void* d_ws, size_t ws_size,
                              hipStream_t stream){
  const float* xyz    = (const float*)d_in[0];
  const float* feat   = (const float*)d_in[1];
  const float* W_pre  = (const float*)d_in[2];
  const float* b_pre  = (const float*)d_in[3];
  const float* W_post = (const float*)d_in[4];
  const float* b_post = (const float*)d_in[5];
  const float* Wp1    = (const float*)d_in[6];
  const float* Wp2    = (const float*)d_in[7];
  const float* Wa1    = (const float*)d_in[8];
  const float* Wa2    = (const float*)d_in[9];
  const float* WQ     = (const float*)d_in[10];
  const float* WK     = (const float*)d_in[11];
  const float* WV     = (const float*)d_in[12];
  const float* Wproj  = (const float*)d_in[13];
  const float* g_dm   = (const float*)d_in[14];
  const float* b_dm   = (const float*)d_in[15];
  const float* g_dp   = (const float*)d_in[16];
  const float* b_dp   = (const float*)d_in[17];
  float* out = (float*)d_out;
  if (ws_size < WS_NEED) return;
  char* ws = (char*)d_ws;
  int* idxw   = (int*)(ws + OFF_IDX);
  u16* wqkvb  = (u16*)(ws + OFF_WQKV);
  u16* wa1b   = (u16*)(ws + OFF_WA1);
  u16* wa2b   = (u16*)(ws + OFF_WA2);
  u16* wp2b   = (u16*)(ws + OFF_WP2);
  u16* wprojb = (u16*)(ws + OFF_WPROJ);
  u16* wpostb = (u16*)(ws + OFF_WPOST);
  u16* mcombb = (u16*)(ws + OFF_MCOMB);
  u16* inp    = (u16*)(ws + OFF_INP);
  u16* lnqkv  = (u16*)(ws + OFF_LNQKV);
  u16* qab    = (u16*)(ws + OFF_QA);
  u16* kab    = (u16*)(ws + OFF_KA);
  u16* resb   = (u16*)(ws + OFF_RES);
  u16* wp1pk  = (u16*)(ws + OFF_WP1PK);

  // 1) fused prologue (weights, wp1 pack, mcomb, kNN, inp GEMM — all independent)
  prep_k<<<3393,256,0,stream>>>(xyz, feat, W_pre, b_pre, WQ, WK, WV, Wa1, Wa2, Wp2,
                                Wproj, W_post, Wp1,
                                wqkvb, wa1b, wa2b, wp2b, wprojb, wpostb,
                                wp1pk, mcombb, idxw, inp);
  // 2) q: qa = ln(inp@WQ.T)@Wa1.T ; k: ka = ...; v: lnv slice
  gemmlnqa_k<<<dim3(256,1,3),512,0,stream>>>(inp, wqkvb, wa1b, qab, kab, lnqkv, g_dm, b_dm);
  // 3) attention
  attn_k<<<4096,512,0,stream>>>(xyz,idxw,lnqkv,qab,kab,mcombb,wp2b,wa2b,wp1pk,resb);
  // 4) out = ln( ln(res@Wproj.T)@Wpost.T + b_post )*g+b + feat
  projpost_k<<<256,512,0,stream>>>(resb, wprojb, wpostb, b_post, g_dm, b_dm, g_dp, b_dp,
                                   feat, out);
}